// Round 6
// baseline (245.924 us; speedup 1.0000x reference)
//
#include <hip/hip_runtime.h>
#include <hip/hip_bf16.h>
#include <math.h>

#define DIM 512
#define NHEAD 8
#define HD 64
#define NBANK 4096
#define NQROWS 4096
#define EPS 1e-5f
#define QSCALE 0.125f
#define PART_ELEMS (NQROWS * DIM)   // one O-partial buffer (bf16 elems)

typedef __attribute__((ext_vector_type(4))) float floatx4;
typedef __attribute__((ext_vector_type(8))) short short8;

__device__ __forceinline__ unsigned short f2bf(float f) {
    unsigned int u = __float_as_uint(f);
    u += 0x7fffu + ((u >> 16) & 1u);          // round-to-nearest-even
    return (unsigned short)(u >> 16);
}
__device__ __forceinline__ float bf2f(unsigned short h) {
    return __uint_as_float(((unsigned int)h) << 16);
}
// packed fp32x2 -> bf16x2 (v_cvt_pk_bf16_f32), low short = a
__device__ __forceinline__ unsigned int pk2(float a, float b) {
    union { __hip_bfloat162 h; unsigned int u; } cvt;
    cvt.h = __float22bfloat162_rn(make_float2(a, b));
    return cvt.u;
}

// ---------------------------------------------------------------------------
// qkv_kernel: fused bf16-MFMA projections, 64x128 tiles.  (unchanged R4)
// ---------------------------------------------------------------------------
__global__ __launch_bounds__(256) void qkv_kernel(
    const float* __restrict__ xq, const float* __restrict__ xk, const float* __restrict__ xv,
    const float* __restrict__ Wqp, const float* __restrict__ Wkp, const float* __restrict__ Wvp,
    const float* __restrict__ qg, const float* __restrict__ qbeta,
    const float* __restrict__ kg, const float* __restrict__ kbeta,
    unsigned short* __restrict__ Qb, unsigned short* __restrict__ Kb,
    unsigned short* __restrict__ VTb)
{
    __shared__ short8 smem[1536];   // A [0,512)=64x64, B [512,1536)=128x64 (24 KB)
    short8* as = smem;
    short8* bs = smem + 512;
    const int tid  = threadIdx.x;
    const int w    = tid >> 6, lane = tid & 63, m = lane & 15, q = lane >> 4;
    const int wr   = w & 1, wc = w >> 1;
    const int row0 = blockIdx.x * 64;
    const int mat  = blockIdx.y >> 2;
    const int col0 = (blockIdx.y & 3) * 128;
    const float* X = (mat == 0) ? xq : (mat == 1) ? xk : xv;
    const float* W = (mat == 0) ? Wqp : (mat == 1) ? Wkp : Wvp;

    floatx4 acc[2][4];
    #pragma unroll
    for (int mt = 0; mt < 2; ++mt)
        #pragma unroll
        for (int nt = 0; nt < 4; ++nt) acc[mt][nt] = (floatx4){0.f, 0.f, 0.f, 0.f};

    for (int k0 = 0; k0 < DIM; k0 += 64) {
        #pragma unroll
        for (int p = 0; p < 6; ++p) {     // 512 A items + 1024 B items
            const int idx = tid + p * 256;
            if (idx < 512) {
                const int row = idx >> 3, seg = idx & 7;
                const float4* pa = (const float4*)(X + (size_t)(row0 + row) * DIM + k0 + seg * 8);
                const float4 a0 = pa[0], a1 = pa[1];
                union { short8 v; unsigned int u[4]; } ta;
                ta.u[0] = pk2(a0.x, a0.y); ta.u[1] = pk2(a0.z, a0.w);
                ta.u[2] = pk2(a1.x, a1.y); ta.u[3] = pk2(a1.z, a1.w);
                as[row * 8 + (seg ^ (row & 7))] = ta.v;
            } else {
                const int j = idx - 512;
                const int row = j >> 3, seg = j & 7;
                const float4* pb = (const float4*)(W + (size_t)(col0 + row) * DIM + k0 + seg * 8);
                const float4 b0 = pb[0], b1 = pb[1];
                union { short8 v; unsigned int u[4]; } tb;
                tb.u[0] = pk2(b0.x, b0.y); tb.u[1] = pk2(b0.z, b0.w);
                tb.u[2] = pk2(b1.x, b1.y); tb.u[3] = pk2(b1.z, b1.w);
                bs[row * 8 + (seg ^ (row & 7))] = tb.v;
            }
        }
        __syncthreads();
        #pragma unroll
        for (int s = 0; s < 2; ++s) {
            short8 af[2], bfr[4];
            #pragma unroll
            for (int mt = 0; mt < 2; ++mt)
                af[mt] = as[(wr * 32 + mt * 16 + m) * 8 + ((s * 4 + q) ^ (m & 7))];
            #pragma unroll
            for (int nt = 0; nt < 4; ++nt)
                bfr[nt] = bs[(wc * 64 + nt * 16 + m) * 8 + ((s * 4 + q) ^ (m & 7))];
            #pragma unroll
            for (int mt = 0; mt < 2; ++mt)
                #pragma unroll
                for (int nt = 0; nt < 4; ++nt)
                    acc[mt][nt] = __builtin_amdgcn_mfma_f32_16x16x32_bf16(af[mt], bfr[nt], acc[mt][nt], 0, 0, 0);
        }
        __syncthreads();
    }

    if (mat < 2) {
        const float* g = (mat == 0) ? qg : kg;
        const float* be = (mat == 0) ? qbeta : kbeta;
        unsigned short* Y = (mat == 0) ? Qb : Kb;
        float gv[4], bv[4];
        #pragma unroll
        for (int nt = 0; nt < 4; ++nt) { gv[nt] = g[nt * 16 + m]; bv[nt] = be[nt * 16 + m]; }
        #pragma unroll
        for (int mt = 0; mt < 2; ++mt) {
            #pragma unroll
            for (int r = 0; r < 4; ++r) {
                float s = 0.f, sq = 0.f;
                #pragma unroll
                for (int nt = 0; nt < 4; ++nt) { const float v = acc[mt][nt][r]; s += v; sq += v * v; }
                s  += __shfl_xor(s, 1);  s  += __shfl_xor(s, 2);  s  += __shfl_xor(s, 4);  s  += __shfl_xor(s, 8);
                sq += __shfl_xor(sq, 1); sq += __shfl_xor(sq, 2); sq += __shfl_xor(sq, 4); sq += __shfl_xor(sq, 8);
                const float mean = s * (1.f / HD);
                const float var  = sq * (1.f / HD) - mean * mean;
                const float rr   = rsqrtf(var + EPS);
                const int grow = row0 + wr * 32 + mt * 16 + q * 4 + r;
                #pragma unroll
                for (int nt = 0; nt < 4; ++nt) {
                    float v = (acc[mt][nt][r] - mean) * rr * gv[nt] + bv[nt];
                    if (mat == 0) v *= QSCALE;
                    Y[(size_t)grow * DIM + col0 + wc * 64 + nt * 16 + m] = f2bf(v);
                }
            }
        }
    } else {
        unsigned short* vt = (unsigned short*)smem;
        #pragma unroll
        for (int mt = 0; mt < 2; ++mt)
            #pragma unroll
            for (int nt = 0; nt < 4; ++nt) {
                const int c  = wc * 64 + nt * 16 + m;
                const int rw = wr * 32 + mt * 16 + q * 4;
                *(unsigned int*)(vt + c * 88 + rw)     = pk2(acc[mt][nt][0], acc[mt][nt][1]);
                *(unsigned int*)(vt + c * 88 + rw + 2) = pk2(acc[mt][nt][2], acc[mt][nt][3]);
            }
        __syncthreads();
        #pragma unroll
        for (int p = 0; p < 4; ++p) {
            const int idx = tid + p * 256;      // 1024 items = 128 cols x 8
            const int c = idx >> 3, sg = idx & 7;
            *(short8*)(VTb + (size_t)(col0 + c) * NBANK + row0 + sg * 8) =
                *(const short8*)(vt + c * 88 + sg * 8);
        }
    }
}

// ---------------------------------------------------------------------------
// attn_kernel: MFMA-bf16 flash attention, register-P (S^T trick), split-4.
// R6: 128-thread blocks (2 waves x 32 q-rows = 64 rows) -> grid (512,4) =
// 2048 blocks, restoring R4 occupancy while keeping R5's zero-LDS-P path.
// V staged BIT-PERMUTED (y[4]=x[2], y[3:2]=x[4:3], y[1:0]=x[1:0], y[5]=x[5])
// so P's C-layout matches the PV B-operand with no shuffles.
// ---------------------------------------------------------------------------
__global__ __launch_bounds__(128) void attn_kernel(
    const unsigned short* __restrict__ Qb, const unsigned short* __restrict__ Kb,
    const unsigned short* __restrict__ VTb, unsigned short* __restrict__ AOp,
    float* __restrict__ sums)
{
    __shared__ short8 smem[1024];       // 16 KB: ks [0,512), vts [512,1024)
    short8* ks  = smem;
    short8* vts = smem + 512;
    const int tid  = threadIdx.x;
    const int w    = tid >> 6;               // 0..1
    const int lane = tid & 63;
    const int m    = lane & 15;
    const int Qd   = lane >> 4;
    const int h    = blockIdx.x & 7;
    const int qgi  = blockIdx.x >> 3;        // 0..63
    const int row0 = qgi * 64;
    const int part = blockIdx.y;
    const int base0 = part * 1024;

    // Q B-operand frags: rows q = row0 + w*32 + mt*16 + m, k = s*32+Qd*8+j
    short8 qf[2][2];
    #pragma unroll
    for (int mt = 0; mt < 2; ++mt)
        #pragma unroll
        for (int s = 0; s < 2; ++s)
            qf[mt][s] = *(const short8*)(Qb + (size_t)(row0 + w * 32 + mt * 16 + m) * DIM
                                         + h * HD + s * 32 + Qd * 8);

    floatx4 of[4][2];                    // [d-tile t2][q-group mt], O^T
    float sump[2] = {0.f, 0.f};
    #pragma unroll
    for (int t = 0; t < 4; ++t)
        #pragma unroll
        for (int mt = 0; mt < 2; ++mt) of[t][mt] = (floatx4){0.f, 0.f, 0.f, 0.f};

    for (int base = base0; base < base0 + 1024; base += 64) {
        __syncthreads();
        // ---- stage K (natural order), 512 items / 128 thr ----
        #pragma unroll
        for (int it = 0; it < 4; ++it) {
            const int idx = tid + it * 128;
            const int n = idx >> 3, seg = idx & 7;
            ks[n * 8 + (seg ^ (n & 7))] =
                *(const short8*)(Kb + (size_t)(base + n) * DIM + h * HD + seg * 8);
        }
        // ---- stage V^T bit-permuted: slot (d, g, j) = V[base + y],
        //      y = (g>>2)*32 + (g&3)*4 + (j<4 ? j : 16+(j&3)) ----
        #pragma unroll
        for (int it = 0; it < 4; ++it) {
            const int idx = tid + it * 128;
            const int d = idx >> 3, g = idx & 7;
            const unsigned short* vp = VTb + (size_t)(h * HD + d) * NBANK + base
                                       + (g >> 2) * 32 + (g & 3) * 4;
            const ushort4 lo = *(const ushort4*)(vp);
            const ushort4 hi = *(const ushort4*)(vp + 16);
            union { short8 v; ushort4 h4[2]; } tv;
            tv.h4[0] = lo; tv.h4[1] = hi;
            vts[d * 8 + (g ^ (d & 7))] = tv.v;
        }
        __syncthreads();

        // ---- S^T = K Q^T : lane holds S[n=t*16+Qd*4+r][q=mt*16+m] ----
        floatx4 st[4][2];
        #pragma unroll
        for (int t = 0; t < 4; ++t)
            #pragma unroll
            for (int mt = 0; mt < 2; ++mt) st[t][mt] = (floatx4){0.f, 0.f, 0.f, 0.f};
        #pragma unroll
        for (int s = 0; s < 2; ++s)
            #pragma unroll
            for (int t = 0; t < 4; ++t) {
                const short8 kf = ks[(t * 16 + m) * 8 + ((s * 4 + Qd) ^ (m & 7))];
                #pragma unroll
                for (int mt = 0; mt < 2; ++mt)
                    st[t][mt] = __builtin_amdgcn_mfma_f32_16x16x32_bf16(kf, qf[mt][s], st[t][mt], 0, 0, 0);
            }

        // ---- P = exp(S^T) in regs; row-sum partials; pack B-frags ----
        float p[4][2][4];
        #pragma unroll
        for (int t = 0; t < 4; ++t)
            #pragma unroll
            for (int mt = 0; mt < 2; ++mt)
                #pragma unroll
                for (int r = 0; r < 4; ++r) {
                    const float e = __expf(st[t][mt][r]);
                    p[t][mt][r] = e;
                    sump[mt] += e;
                }
        union { short8 v; unsigned int u[4]; } pf[2][2];   // [mt][s2]
        #pragma unroll
        for (int mt = 0; mt < 2; ++mt)
            #pragma unroll
            for (int s2 = 0; s2 < 2; ++s2)
                #pragma unroll
                for (int u = 0; u < 4; ++u)
                    pf[mt][s2].u[u] = pk2(p[s2 * 2 + (u >> 1)][mt][(u & 1) * 2],
                                          p[s2 * 2 + (u >> 1)][mt][(u & 1) * 2 + 1]);

        // ---- O^T += V^T P : vf rows d, pf rows q ----
        #pragma unroll
        for (int s2 = 0; s2 < 2; ++s2)
            #pragma unroll
            for (int t2 = 0; t2 < 4; ++t2) {
                const short8 vf = vts[(t2 * 16 + m) * 8 + ((s2 * 4 + Qd) ^ (m & 7))];
                #pragma unroll
                for (int mt = 0; mt < 2; ++mt)
                    of[t2][mt] = __builtin_amdgcn_mfma_f32_16x16x32_bf16(vf, pf[mt][s2].v, of[t2][mt], 0, 0, 0);
            }
    }

    // ---- denominators: reduce per-lane partials across quads ----
    #pragma unroll
    for (int mt = 0; mt < 2; ++mt) {
        float s = sump[mt];
        s += __shfl_xor(s, 16);
        s += __shfl_xor(s, 32);
        sump[mt] = s;                    // total for q = row0+w*32+mt*16+m
    }
    if (Qd == 0) {
        #pragma unroll
        for (int mt = 0; mt < 2; ++mt)
            sums[((size_t)part * NQROWS + row0 + w * 32 + mt * 16 + m) * NHEAD + h] = sump[mt];
    }

    // ---- O^T -> O via LDS (smem dead), coalesced bf16 b128 stores ----
    __syncthreads();
    unsigned int* ob = (unsigned int*)smem;   // O[q 0..63][d/2 0..31] u32-pairs
    #pragma unroll
    for (int t2 = 0; t2 < 4; ++t2)
        #pragma unroll
        for (int mt = 0; mt < 2; ++mt) {
            const int q  = w * 32 + mt * 16 + m;
            const int blk = t2 * 2 + (Qd >> 1);            // 16B block in row
            const int sub = (Qd & 1) * 2;
            const int bs  = (blk ^ (q & 7)) * 4;
            ob[q * 32 + bs + sub]     = pk2(of[t2][mt][0], of[t2][mt][1]);
            ob[q * 32 + bs + sub + 1] = pk2(of[t2][mt][2], of[t2][mt][3]);
        }
    __syncthreads();
    #pragma unroll
    for (int pp = 0; pp < 4; ++pp) {
        const int idx = tid + pp * 128;        // 512 = 64 q x 8 segs
        const int q = idx >> 3, sg = idx & 7;
        *(short8*)(AOp + (size_t)part * PART_ELEMS + (size_t)(row0 + q) * DIM + h * HD + sg * 8) =
            smem[q * 8 + (sg ^ (q & 7))];
    }
}

// ---------------------------------------------------------------------------
// combine_kernel: AO = (sum_p O_p) / (sum_p s_p), bf16 out; fused final-LN
// row stats.  (unchanged R4)
// ---------------------------------------------------------------------------
__global__ __launch_bounds__(256) void combine_kernel(
    const unsigned short* __restrict__ AOp, const float* __restrict__ sums,
    unsigned short* __restrict__ AO, float* __restrict__ meanv, float* __restrict__ rstdv)
{
    __shared__ float rs[256], rq[256];
    const int tid = threadIdx.x;
    const int row = blockIdx.x * 2 + (tid >> 7);
    const int t   = tid & 127;                 // 4 cols per thread
    const int h   = t >> 4;

    float stot = 0.f;
    #pragma unroll
    for (int p = 0; p < 4; ++p)
        stot += sums[((size_t)p * NQROWS + row) * NHEAD + h];

    float o[4] = {0.f, 0.f, 0.f, 0.f};
    #pragma unroll
    for (int p = 0; p < 4; ++p) {
        const ushort4 u = *(const ushort4*)(AOp + (size_t)p * PART_ELEMS + (size_t)row * DIM + t * 4);
        o[0] += bf2f(u.x); o[1] += bf2f(u.y); o[2] += bf2f(u.z); o[3] += bf2f(u.w);
    }
    const float inv = 1.0f / stot;
    float v0 = o[0] * inv, v1 = o[1] * inv, v2 = o[2] * inv, v3 = o[3] * inv;

    uint2 packed;
    packed.x = pk2(v0, v1); packed.y = pk2(v2, v3);
    *(uint2*)(AO + (size_t)row * DIM + t * 4) = packed;

    rs[tid] = v0 + v1 + v2 + v3;
    rq[tid] = v0 * v0 + v1 * v1 + v2 * v2 + v3 * v3;
    __syncthreads();
    #pragma unroll
    for (int off = 64; off > 0; off >>= 1) {
        if (t < off) { rs[tid] += rs[tid + off]; rq[tid] += rq[tid + off]; }
        __syncthreads();
    }
    if (t == 0) {
        const float mean = rs[tid] * (1.f / DIM);
        const float var  = rq[tid] * (1.f / DIM) - mean * mean;
        meanv[row] = mean;
        rstdv[row] = rsqrtf(var + EPS);
    }
}

// ---------------------------------------------------------------------------
// final_kernel: out = LN_512(AO) @ Wproj^T.  (unchanged R4)
// ---------------------------------------------------------------------------
__global__ __launch_bounds__(256) void final_kernel(
    const unsigned short* __restrict__ AO, const float* __restrict__ W,
    const float* __restrict__ meanv, const float* __restrict__ rstdv,
    const float* __restrict__ g, const float* __restrict__ be,
    float* __restrict__ out)
{
    __shared__ short8 fs[1024];            // A [0,512)=64x64, B [512,1024)=64x64
    __shared__ float gls[512], bls[512];
    const int tid  = threadIdx.x;
    const int w    = tid >> 6, lane = tid & 63, m = lane & 15, q = lane >> 4;
    const int row0 = blockIdx.x * 64;
    const int col0 = blockIdx.y * 64;

    #pragma unroll
    for (int i = 0; i < 2; ++i) { gls[tid + i * 256] = g[tid + i * 256]; bls[tid + i * 256] = be[tid + i * 256]; }

    floatx4 acc[4];
    #pragma unroll
    for (int mt = 0; mt < 4; ++mt) acc[mt] = (floatx4){0.f, 0.f, 0.f, 0.f};
    __syncthreads();

    for (int k0 = 0; k0 < DIM; k0 += 64) {
        #pragma unroll
        for (int p = 0; p < 4; ++p) {      // 512 A items + 512 B items
            const int idx = tid + p * 256;
            if (idx < 512) {
                const int row = idx >> 3, seg = idx & 7;
                const short8 a = *(const short8*)(AO + (size_t)(row0 + row) * DIM + k0 + seg * 8);
                const float mm = meanv[row0 + row], rr = rstdv[row0 + row];
                const float* gp = gls + k0 + seg * 8;
                const float* bp = bls + k0 + seg * 8;
                float v[8];
                #pragma unroll
                for (int j = 0; j < 8; ++j)
                    v[j] = (bf2f((unsigned short)a[j]) - mm) * rr * gp[j] + bp[j];
                union { short8 s; unsigned int u[4]; } ta;
                ta.u[0] = pk2(v[0], v[1]); ta.u[1] = pk2(v[2], v[3]);
                ta.u[2] = pk2(v[4], v[5]); ta.u[3] = pk2(v[6], v[7]);
                fs[row * 8 + (seg ^ (row & 7))] = ta.s;
            } else {
                const int j = idx - 512;
                const int row = j >> 3, seg = j & 7;
                const float4* pb = (const float4*)(W + (size_t)(col0 + row) * DIM + k0 + seg * 8);
                const float4 b0 = pb[0], b1 = pb[1];
                union { short8 s; unsigned int u[4]; } tb;
                tb.u[0] = pk2(b0.x, b0.y); tb.u[1] = pk2(b0.z, b0.w);
                tb.u[2] = pk2(b1.x, b1.y); tb.u[3] = pk2(b1.z, b1.w);
                fs[512 + row * 8 + (seg ^ (row & 7))] = tb.s;
            }
        }
        __syncthreads();
        #pragma unroll
        for (int s = 0; s < 2; ++s) {
            short8 af[4];
            #pragma unroll
            for (int mt = 0; mt < 4; ++mt)
                af[mt] = fs[(mt * 16 + m) * 8 + ((s * 4 + q) ^ (m & 7))];
            const short8 bfr = fs[512 + (w * 16 + m) * 8 + ((s * 4 + q) ^ (m & 7))];
            #pragma unroll
            for (int mt = 0; mt < 4; ++mt)
                acc[mt] = __builtin_amdgcn_mfma_f32_16x16x32_bf16(af[mt], bfr, acc[mt], 0, 0, 0);
        }
        __syncthreads();
    }

    #pragma unroll
    for (int mt = 0; mt < 4; ++mt)
        #pragma unroll
        for (int r = 0; r < 4; ++r)
            out[(size_t)(row0 + mt * 16 + q * 4 + r) * DIM + col0 + w * 16 + m] = acc[mt][r];
}

// ---------------------------------------------------------------------------
extern "C" void kernel_launch(void* const* d_in, const int* in_sizes, int n_in,
                              void* d_out, int out_size, void* d_ws, size_t ws_size,
                              hipStream_t stream)
{
    const float* x_q = (const float*)d_in[0];
    const float* x_k = (const float*)d_in[1];
    const float* x_v = (const float*)d_in[2];
    const float* Wq  = (const float*)d_in[3];
    const float* Wk  = (const float*)d_in[4];
    const float* Wv  = (const float*)d_in[5];
    const float* Wp  = (const float*)d_in[6];
    const float* qg  = (const float*)d_in[7];
    const float* qb  = (const float*)d_in[8];
    const float* kg  = (const float*)d_in[9];
    const float* kb  = (const float*)d_in[10];
    const float* ng  = (const float*)d_in[11];
    const float* nb  = (const float*)d_in[12];
    float* out = (float*)d_out;

    // ws: Qb|Kb|VTb (bf16, 4 MB each) | AOp (bf16, 4x4 MB) | sums 512 KB |
    //     stats 32 KB.  AO (bf16) aliases Qb (dead after attn). Total ~28.6 MB.
    unsigned short* Qb   = (unsigned short*)d_ws;
    unsigned short* Kb   = Qb  + (size_t)NQROWS * DIM;
    unsigned short* VTb  = Kb  + (size_t)NBANK * DIM;
    unsigned short* AOp  = VTb + (size_t)NBANK * DIM;
    float*          sums = (float*)(AOp + (size_t)4 * PART_ELEMS);
    float*          meanv = sums + (size_t)4 * NQROWS * NHEAD;
    float*          rstdv = meanv + NQROWS;
    unsigned short* AO   = Qb;   // alias: Qb dead after attn_kernel

    qkv_kernel<<<dim3(64, 12), 256, 0, stream>>>(x_q, x_k, x_v, Wq, Wk, Wv,
                                                 qg, qb, kg, kb, Qb, Kb, VTb);
    attn_kernel<<<dim3(512, 4), 128, 0, stream>>>(Qb, Kb, VTb, AOp, sums);
    combine_kernel<<<NQROWS / 2, 256, 0, stream>>>(AOp, sums, AO, meanv, rstdv);
    final_kernel<<<dim3(64, 8), 256, 0, stream>>>(AO, Wp, meanv, rstdv, ng, nb, out);
}

// Round 7
// 188.100 us; speedup vs baseline: 1.3074x; 1.3074x over previous
//
#include <hip/hip_runtime.h>
#include <hip/hip_bf16.h>
#include <math.h>

#define DIM 512
#define NHEAD 8
#define HD 64
#define NBANK 4096
#define NQROWS 4096
#define EPS 1e-5f
#define QSCALE 0.125f
#define PART_ELEMS (NQROWS * DIM)   // one O-partial buffer (bf16 elems)

typedef __attribute__((ext_vector_type(4))) float floatx4;
typedef __attribute__((ext_vector_type(8))) short short8;

__device__ __forceinline__ unsigned short f2bf(float f) {
    unsigned int u = __float_as_uint(f);
    u += 0x7fffu + ((u >> 16) & 1u);          // round-to-nearest-even
    return (unsigned short)(u >> 16);
}
__device__ __forceinline__ float bf2f(unsigned short h) {
    return __uint_as_float(((unsigned int)h) << 16);
}
// packed fp32x2 -> bf16x2 (v_cvt_pk_bf16_f32), low short = a
__device__ __forceinline__ unsigned int pk2(float a, float b) {
    union { __hip_bfloat162 h; unsigned int u; } cvt;
    cvt.h = __float22bfloat162_rn(make_float2(a, b));
    return cvt.u;
}

// ---------------------------------------------------------------------------
// qkv_kernel: fused bf16-MFMA projections, 64x128 tiles.  (unchanged R4)
// ---------------------------------------------------------------------------
__global__ __launch_bounds__(256) void qkv_kernel(
    const float* __restrict__ xq, const float* __restrict__ xk, const float* __restrict__ xv,
    const float* __restrict__ Wqp, const float* __restrict__ Wkp, const float* __restrict__ Wvp,
    const float* __restrict__ qg, const float* __restrict__ qbeta,
    const float* __restrict__ kg, const float* __restrict__ kbeta,
    unsigned short* __restrict__ Qb, unsigned short* __restrict__ Kb,
    unsigned short* __restrict__ VTb)
{
    __shared__ short8 smem[1536];   // A [0,512)=64x64, B [512,1536)=128x64 (24 KB)
    short8* as = smem;
    short8* bs = smem + 512;
    const int tid  = threadIdx.x;
    const int w    = tid >> 6, lane = tid & 63, m = lane & 15, q = lane >> 4;
    const int wr   = w & 1, wc = w >> 1;
    const int row0 = blockIdx.x * 64;
    const int mat  = blockIdx.y >> 2;
    const int col0 = (blockIdx.y & 3) * 128;
    const float* X = (mat == 0) ? xq : (mat == 1) ? xk : xv;
    const float* W = (mat == 0) ? Wqp : (mat == 1) ? Wkp : Wvp;

    floatx4 acc[2][4];
    #pragma unroll
    for (int mt = 0; mt < 2; ++mt)
        #pragma unroll
        for (int nt = 0; nt < 4; ++nt) acc[mt][nt] = (floatx4){0.f, 0.f, 0.f, 0.f};

    for (int k0 = 0; k0 < DIM; k0 += 64) {
        #pragma unroll
        for (int p = 0; p < 6; ++p) {     // 512 A items + 1024 B items
            const int idx = tid + p * 256;
            if (idx < 512) {
                const int row = idx >> 3, seg = idx & 7;
                const float4* pa = (const float4*)(X + (size_t)(row0 + row) * DIM + k0 + seg * 8);
                const float4 a0 = pa[0], a1 = pa[1];
                union { short8 v; unsigned int u[4]; } ta;
                ta.u[0] = pk2(a0.x, a0.y); ta.u[1] = pk2(a0.z, a0.w);
                ta.u[2] = pk2(a1.x, a1.y); ta.u[3] = pk2(a1.z, a1.w);
                as[row * 8 + (seg ^ (row & 7))] = ta.v;
            } else {
                const int j = idx - 512;
                const int row = j >> 3, seg = j & 7;
                const float4* pb = (const float4*)(W + (size_t)(col0 + row) * DIM + k0 + seg * 8);
                const float4 b0 = pb[0], b1 = pb[1];
                union { short8 v; unsigned int u[4]; } tb;
                tb.u[0] = pk2(b0.x, b0.y); tb.u[1] = pk2(b0.z, b0.w);
                tb.u[2] = pk2(b1.x, b1.y); tb.u[3] = pk2(b1.z, b1.w);
                bs[row * 8 + (seg ^ (row & 7))] = tb.v;
            }
        }
        __syncthreads();
        #pragma unroll
        for (int s = 0; s < 2; ++s) {
            short8 af[2], bfr[4];
            #pragma unroll
            for (int mt = 0; mt < 2; ++mt)
                af[mt] = as[(wr * 32 + mt * 16 + m) * 8 + ((s * 4 + q) ^ (m & 7))];
            #pragma unroll
            for (int nt = 0; nt < 4; ++nt)
                bfr[nt] = bs[(wc * 64 + nt * 16 + m) * 8 + ((s * 4 + q) ^ (m & 7))];
            #pragma unroll
            for (int mt = 0; mt < 2; ++mt)
                #pragma unroll
                for (int nt = 0; nt < 4; ++nt)
                    acc[mt][nt] = __builtin_amdgcn_mfma_f32_16x16x32_bf16(af[mt], bfr[nt], acc[mt][nt], 0, 0, 0);
        }
        __syncthreads();
    }

    if (mat < 2) {
        const float* g = (mat == 0) ? qg : kg;
        const float* be = (mat == 0) ? qbeta : kbeta;
        unsigned short* Y = (mat == 0) ? Qb : Kb;
        float gv[4], bv[4];
        #pragma unroll
        for (int nt = 0; nt < 4; ++nt) { gv[nt] = g[nt * 16 + m]; bv[nt] = be[nt * 16 + m]; }
        #pragma unroll
        for (int mt = 0; mt < 2; ++mt) {
            #pragma unroll
            for (int r = 0; r < 4; ++r) {
                float s = 0.f, sq = 0.f;
                #pragma unroll
                for (int nt = 0; nt < 4; ++nt) { const float v = acc[mt][nt][r]; s += v; sq += v * v; }
                s  += __shfl_xor(s, 1);  s  += __shfl_xor(s, 2);  s  += __shfl_xor(s, 4);  s  += __shfl_xor(s, 8);
                sq += __shfl_xor(sq, 1); sq += __shfl_xor(sq, 2); sq += __shfl_xor(sq, 4); sq += __shfl_xor(sq, 8);
                const float mean = s * (1.f / HD);
                const float var  = sq * (1.f / HD) - mean * mean;
                const float rr   = rsqrtf(var + EPS);
                const int grow = row0 + wr * 32 + mt * 16 + q * 4 + r;
                #pragma unroll
                for (int nt = 0; nt < 4; ++nt) {
                    float v = (acc[mt][nt][r] - mean) * rr * gv[nt] + bv[nt];
                    if (mat == 0) v *= QSCALE;
                    Y[(size_t)grow * DIM + col0 + wc * 64 + nt * 16 + m] = f2bf(v);
                }
            }
        }
    } else {
        unsigned short* vt = (unsigned short*)smem;
        #pragma unroll
        for (int mt = 0; mt < 2; ++mt)
            #pragma unroll
            for (int nt = 0; nt < 4; ++nt) {
                const int c  = wc * 64 + nt * 16 + m;
                const int rw = wr * 32 + mt * 16 + q * 4;
                *(unsigned int*)(vt + c * 88 + rw)     = pk2(acc[mt][nt][0], acc[mt][nt][1]);
                *(unsigned int*)(vt + c * 88 + rw + 2) = pk2(acc[mt][nt][2], acc[mt][nt][3]);
            }
        __syncthreads();
        #pragma unroll
        for (int p = 0; p < 4; ++p) {
            const int idx = tid + p * 256;      // 1024 items = 128 cols x 8
            const int c = idx >> 3, sg = idx & 7;
            *(short8*)(VTb + (size_t)(col0 + c) * NBANK + row0 + sg * 8) =
                *(const short8*)(vt + c * 88 + sg * 8);
        }
    }
}

// ---------------------------------------------------------------------------
// attn_kernel R7: R4 geometry (256 thr, 4 waves x 16 q-rows, grid (512,4))
// + register-P (S^T trick, bit-permuted V staging)
// + register double-buffered K/V prefetch (global load latency off the chain).
// ---------------------------------------------------------------------------
__global__ __launch_bounds__(256) void attn_kernel(
    const unsigned short* __restrict__ Qb, const unsigned short* __restrict__ Kb,
    const unsigned short* __restrict__ VTb, unsigned short* __restrict__ AOp,
    float* __restrict__ sums)
{
    __shared__ short8 smem[1024];       // 16 KB: ks [0,512), vts [512,1024)
    short8* ks  = smem;
    short8* vts = smem + 512;
    const int tid  = threadIdx.x;
    const int w    = tid >> 6;               // 0..3
    const int lane = tid & 63;
    const int m    = lane & 15;
    const int Qd   = lane >> 4;
    const int h    = blockIdx.x & 7;
    const int qgi  = blockIdx.x >> 3;        // 0..63
    const int row0 = qgi * 64;
    const int part = blockIdx.y;
    const int base0 = part * 1024;

    // staging assignments (fixed per thread): 2 K items + 2 V items
    const int sn0 = tid >> 3,        sseg = tid & 7;           // K/V item 0
    const int sn1 = (tid + 256) >> 3;                          // item 1 (same seg)
    const unsigned short* kp0 = Kb + (size_t)sn0 * DIM + h * HD + sseg * 8;
    const unsigned short* kp1 = Kb + (size_t)sn1 * DIM + h * HD + sseg * 8;
    const unsigned short* vp0 = VTb + (size_t)(h * HD + sn0) * NBANK + (sseg >> 2) * 32 + (sseg & 3) * 4;
    const unsigned short* vp1 = VTb + (size_t)(h * HD + sn1) * NBANK + (sseg >> 2) * 32 + (sseg & 3) * 4;

    // Q B-operand frags: rows q = row0 + w*16 + m, k = s*32 + Qd*8 + j
    short8 qf[2];
    #pragma unroll
    for (int s = 0; s < 2; ++s)
        qf[s] = *(const short8*)(Qb + (size_t)(row0 + w * 16 + m) * DIM + h * HD + s * 32 + Qd * 8);

    floatx4 of[4];                       // O^T accumulators
    float sump = 0.f;
    #pragma unroll
    for (int t = 0; t < 4; ++t) of[t] = (floatx4){0.f, 0.f, 0.f, 0.f};

    short8 kreg0, kreg1;
    ushort4 vlo0, vhi0, vlo1, vhi1;

    // prefetch chunk 0
    {
        kreg0 = *(const short8*)(kp0 + (size_t)base0 * DIM);
        kreg1 = *(const short8*)(kp1 + (size_t)base0 * DIM);
        vlo0 = *(const ushort4*)(vp0 + base0);  vhi0 = *(const ushort4*)(vp0 + base0 + 16);
        vlo1 = *(const ushort4*)(vp1 + base0);  vhi1 = *(const ushort4*)(vp1 + base0 + 16);
    }

    for (int c = 0; c < 16; ++c) {
        __syncthreads();                  // prior chunk's LDS reads complete
        // ---- write prefetched regs -> LDS ----
        ks[sn0 * 8 + (sseg ^ (sn0 & 7))] = kreg0;
        ks[sn1 * 8 + (sseg ^ (sn1 & 7))] = kreg1;
        {
            union { short8 v; ushort4 h4[2]; } tv;
            tv.h4[0] = vlo0; tv.h4[1] = vhi0;
            vts[sn0 * 8 + (sseg ^ (sn0 & 7))] = tv.v;
            tv.h4[0] = vlo1; tv.h4[1] = vhi1;
            vts[sn1 * 8 + (sseg ^ (sn1 & 7))] = tv.v;
        }
        __syncthreads();
        // ---- issue next chunk's loads (latency overlaps compute below) ----
        if (c < 15) {
            const int nb = base0 + (c + 1) * 64;
            kreg0 = *(const short8*)(kp0 + (size_t)nb * DIM);
            kreg1 = *(const short8*)(kp1 + (size_t)nb * DIM);
            vlo0 = *(const ushort4*)(vp0 + nb);  vhi0 = *(const ushort4*)(vp0 + nb + 16);
            vlo1 = *(const ushort4*)(vp1 + nb);  vhi1 = *(const ushort4*)(vp1 + nb + 16);
        }

        // ---- S^T = K Q^T : lane holds S[n = t*16 + Qd*4 + r][q = m] ----
        floatx4 st[4];
        #pragma unroll
        for (int t = 0; t < 4; ++t) st[t] = (floatx4){0.f, 0.f, 0.f, 0.f};
        #pragma unroll
        for (int s = 0; s < 2; ++s)
            #pragma unroll
            for (int t = 0; t < 4; ++t) {
                const short8 kf = ks[(t * 16 + m) * 8 + ((s * 4 + Qd) ^ (m & 7))];
                st[t] = __builtin_amdgcn_mfma_f32_16x16x32_bf16(kf, qf[s], st[t], 0, 0, 0);
            }

        // ---- P = exp(S^T) in regs; per-lane row-sum partials; pack B-frags ----
        float p[4][4];
        #pragma unroll
        for (int t = 0; t < 4; ++t)
            #pragma unroll
            for (int r = 0; r < 4; ++r) {
                const float e = __expf(st[t][r]);
                p[t][r] = e;
                sump += e;
            }
        union { short8 v; unsigned int u[4]; } pf[2];   // [s2]
        #pragma unroll
        for (int s2 = 0; s2 < 2; ++s2)
            #pragma unroll
            for (int u = 0; u < 4; ++u)
                pf[s2].u[u] = pk2(p[s2 * 2 + (u >> 1)][(u & 1) * 2],
                                  p[s2 * 2 + (u >> 1)][(u & 1) * 2 + 1]);

        // ---- O^T += V^T P (bit-permuted V absorbs the layout mismatch) ----
        #pragma unroll
        for (int s2 = 0; s2 < 2; ++s2)
            #pragma unroll
            for (int t2 = 0; t2 < 4; ++t2) {
                const short8 vf = vts[(t2 * 16 + m) * 8 + ((s2 * 4 + Qd) ^ (m & 7))];
                of[t2] = __builtin_amdgcn_mfma_f32_16x16x32_bf16(vf, pf[s2].v, of[t2], 0, 0, 0);
            }
    }

    // ---- denominators: reduce per-lane partials across quads ----
    {
        float s = sump;
        s += __shfl_xor(s, 16);
        s += __shfl_xor(s, 32);
        sump = s;                        // total for q = row0 + w*16 + m
    }
    if (Qd == 0)
        sums[((size_t)part * NQROWS + row0 + w * 16 + m) * NHEAD + h] = sump;

    // ---- O^T -> O via LDS (smem dead), coalesced bf16 b128 stores ----
    __syncthreads();
    unsigned int* ob = (unsigned int*)smem;   // O[q 0..63][d/2 0..31] u32
    #pragma unroll
    for (int t2 = 0; t2 < 4; ++t2) {
        const int q  = w * 16 + m;
        const int blk = t2 * 2 + (Qd >> 1);            // 16B block in row
        const int sub = (Qd & 1) * 2;
        const int bs  = (blk ^ (q & 7)) * 4;
        ob[q * 32 + bs + sub]     = pk2(of[t2][0], of[t2][1]);
        ob[q * 32 + bs + sub + 1] = pk2(of[t2][2], of[t2][3]);
    }
    __syncthreads();
    #pragma unroll
    for (int pp = 0; pp < 2; ++pp) {
        const int idx = tid + pp * 256;        // 512 = 64 q x 8 segs
        const int q = idx >> 3, sg = idx & 7;
        *(short8*)(AOp + (size_t)part * PART_ELEMS + (size_t)(row0 + q) * DIM + h * HD + sg * 8) =
            smem[q * 8 + (sg ^ (q & 7))];
    }
}

// ---------------------------------------------------------------------------
// combine_kernel: AO = (sum_p O_p) / (sum_p s_p), bf16 out; fused final-LN
// row stats.  (unchanged R4)
// ---------------------------------------------------------------------------
__global__ __launch_bounds__(256) void combine_kernel(
    const unsigned short* __restrict__ AOp, const float* __restrict__ sums,
    unsigned short* __restrict__ AO, float* __restrict__ meanv, float* __restrict__ rstdv)
{
    __shared__ float rs[256], rq[256];
    const int tid = threadIdx.x;
    const int row = blockIdx.x * 2 + (tid >> 7);
    const int t   = tid & 127;                 // 4 cols per thread
    const int h   = t >> 4;

    float stot = 0.f;
    #pragma unroll
    for (int p = 0; p < 4; ++p)
        stot += sums[((size_t)p * NQROWS + row) * NHEAD + h];

    float o[4] = {0.f, 0.f, 0.f, 0.f};
    #pragma unroll
    for (int p = 0; p < 4; ++p) {
        const ushort4 u = *(const ushort4*)(AOp + (size_t)p * PART_ELEMS + (size_t)row * DIM + t * 4);
        o[0] += bf2f(u.x); o[1] += bf2f(u.y); o[2] += bf2f(u.z); o[3] += bf2f(u.w);
    }
    const float inv = 1.0f / stot;
    float v0 = o[0] * inv, v1 = o[1] * inv, v2 = o[2] * inv, v3 = o[3] * inv;

    uint2 packed;
    packed.x = pk2(v0, v1); packed.y = pk2(v2, v3);
    *(uint2*)(AO + (size_t)row * DIM + t * 4) = packed;

    rs[tid] = v0 + v1 + v2 + v3;
    rq[tid] = v0 * v0 + v1 * v1 + v2 * v2 + v3 * v3;
    __syncthreads();
    #pragma unroll
    for (int off = 64; off > 0; off >>= 1) {
        if (t < off) { rs[tid] += rs[tid + off]; rq[tid] += rq[tid + off]; }
        __syncthreads();
    }
    if (t == 0) {
        const float mean = rs[tid] * (1.f / DIM);
        const float var  = rq[tid] * (1.f / DIM) - mean * mean;
        meanv[row] = mean;
        rstdv[row] = rsqrtf(var + EPS);
    }
}

// ---------------------------------------------------------------------------
// final_kernel: out = LN_512(AO) @ Wproj^T.  (unchanged R4)
// ---------------------------------------------------------------------------
__global__ __launch_bounds__(256) void final_kernel(
    const unsigned short* __restrict__ AO, const float* __restrict__ W,
    const float* __restrict__ meanv, const float* __restrict__ rstdv,
    const float* __restrict__ g, const float* __restrict__ be,
    float* __restrict__ out)
{
    __shared__ short8 fs[1024];            // A [0,512)=64x64, B [512,1024)=64x64
    __shared__ float gls[512], bls[512];
    const int tid  = threadIdx.x;
    const int w    = tid >> 6, lane = tid & 63, m = lane & 15, q = lane >> 4;
    const int row0 = blockIdx.x * 64;
    const int col0 = blockIdx.y * 64;

    #pragma unroll
    for (int i = 0; i < 2; ++i) { gls[tid + i * 256] = g[tid + i * 256]; bls[tid + i * 256] = be[tid + i * 256]; }

    floatx4 acc[4];
    #pragma unroll
    for (int mt = 0; mt < 4; ++mt) acc[mt] = (floatx4){0.f, 0.f, 0.f, 0.f};
    __syncthreads();

    for (int k0 = 0; k0 < DIM; k0 += 64) {
        #pragma unroll
        for (int p = 0; p < 4; ++p) {      // 512 A items + 512 B items
            const int idx = tid + p * 256;
            if (idx < 512) {
                const int row = idx >> 3, seg = idx & 7;
                const short8 a = *(const short8*)(AO + (size_t)(row0 + row) * DIM + k0 + seg * 8);
                const float mm = meanv[row0 + row], rr = rstdv[row0 + row];
                const float* gp = gls + k0 + seg * 8;
                const float* bp = bls + k0 + seg * 8;
                float v[8];
                #pragma unroll
                for (int j = 0; j < 8; ++j)
                    v[j] = (bf2f((unsigned short)a[j]) - mm) * rr * gp[j] + bp[j];
                union { short8 s; unsigned int u[4]; } ta;
                ta.u[0] = pk2(v[0], v[1]); ta.u[1] = pk2(v[2], v[3]);
                ta.u[2] = pk2(v[4], v[5]); ta.u[3] = pk2(v[6], v[7]);
                fs[row * 8 + (seg ^ (row & 7))] = ta.s;
            } else {
                const int j = idx - 512;
                const int row = j >> 3, seg = j & 7;
                const float4* pb = (const float4*)(W + (size_t)(col0 + row) * DIM + k0 + seg * 8);
                const float4 b0 = pb[0], b1 = pb[1];
                union { short8 s; unsigned int u[4]; } tb;
                tb.u[0] = pk2(b0.x, b0.y); tb.u[1] = pk2(b0.z, b0.w);
                tb.u[2] = pk2(b1.x, b1.y); tb.u[3] = pk2(b1.z, b1.w);
                fs[512 + row * 8 + (seg ^ (row & 7))] = tb.s;
            }
        }
        __syncthreads();
        #pragma unroll
        for (int s = 0; s < 2; ++s) {
            short8 af[4];
            #pragma unroll
            for (int mt = 0; mt < 4; ++mt)
                af[mt] = fs[(mt * 16 + m) * 8 + ((s * 4 + q) ^ (m & 7))];
            const short8 bfr = fs[512 + (w * 16 + m) * 8 + ((s * 4 + q) ^ (m & 7))];
            #pragma unroll
            for (int mt = 0; mt < 4; ++mt)
                acc[mt] = __builtin_amdgcn_mfma_f32_16x16x32_bf16(af[mt], bfr, acc[mt], 0, 0, 0);
        }
        __syncthreads();
    }

    #pragma unroll
    for (int mt = 0; mt < 4; ++mt)
        #pragma unroll
        for (int r = 0; r < 4; ++r)
            out[(size_t)(row0 + mt * 16 + q * 4 + r) * DIM + col0 + w * 16 + m] = acc[mt][r];
}

// ---------------------------------------------------------------------------
extern "C" void kernel_launch(void* const* d_in, const int* in_sizes, int n_in,
                              void* d_out, int out_size, void* d_ws, size_t ws_size,
                              hipStream_t stream)
{
    const float* x_q = (const float*)d_in[0];
    const float* x_k = (const float*)d_in[1];
    const float* x_v = (const float*)d_in[2];
    const float* Wq  = (const float*)d_in[3];
    const float* Wk  = (const float*)d_in[4];
    const float* Wv  = (const float*)d_in[5];
    const float* Wp  = (const float*)d_in[6];
    const float* qg  = (const float*)d_in[7];
    const float* qb  = (const float*)d_in[8];
    const float* kg  = (const float*)d_in[9];
    const float* kb  = (const float*)d_in[10];
    const float* ng  = (const float*)d_in[11];
    const float* nb  = (const float*)d_in[12];
    float* out = (float*)d_out;

    // ws: Qb|Kb|VTb (bf16, 4 MB each) | AOp (bf16, 4x4 MB) | sums 512 KB |
    //     stats 32 KB.  AO (bf16) aliases Qb (dead after attn). Total ~28.6 MB.
    unsigned short* Qb   = (unsigned short*)d_ws;
    unsigned short* Kb   = Qb  + (size_t)NQROWS * DIM;
    unsigned short* VTb  = Kb  + (size_t)NBANK * DIM;
    unsigned short* AOp  = VTb + (size_t)NBANK * DIM;
    float*          sums = (float*)(AOp + (size_t)4 * PART_ELEMS);
    float*          meanv = sums + (size_t)4 * NQROWS * NHEAD;
    float*          rstdv = meanv + NQROWS;
    unsigned short* AO   = Qb;   // alias: Qb dead after attn_kernel

    qkv_kernel<<<dim3(64, 12), 256, 0, stream>>>(x_q, x_k, x_v, Wq, Wk, Wv,
                                                 qg, qb, kg, kb, Qb, Kb, VTb);
    attn_kernel<<<dim3(512, 4), 256, 0, stream>>>(Qb, Kb, VTb, AOp, sums);
    combine_kernel<<<NQROWS / 2, 256, 0, stream>>>(AOp, sums, AO, meanv, rstdv);
    final_kernel<<<dim3(64, 8), 256, 0, stream>>>(AO, Wp, meanv, rstdv, ng, nb, out);
}

// Round 8
// 180.088 us; speedup vs baseline: 1.3656x; 1.0445x over previous
//
#include <hip/hip_runtime.h>
#include <hip/hip_bf16.h>
#include <math.h>

#define DIM 512
#define NHEAD 8
#define HD 64
#define NBANK 4096
#define NQROWS 4096
#define EPS 1e-5f
#define QSCALE 0.125f
#define PART_ELEMS (NQROWS * DIM)   // one O-partial buffer (bf16 elems)

typedef __attribute__((ext_vector_type(4))) float floatx4;
typedef __attribute__((ext_vector_type(8))) short short8;

__device__ __forceinline__ unsigned short f2bf(float f) {
    unsigned int u = __float_as_uint(f);
    u += 0x7fffu + ((u >> 16) & 1u);          // round-to-nearest-even
    return (unsigned short)(u >> 16);
}
__device__ __forceinline__ float bf2f(unsigned short h) {
    return __uint_as_float(((unsigned int)h) << 16);
}
// packed fp32x2 -> bf16x2 (v_cvt_pk_bf16_f32), low short = a
__device__ __forceinline__ unsigned int pk2(float a, float b) {
    union { __hip_bfloat162 h; unsigned int u; } cvt;
    cvt.h = __float22bfloat162_rn(make_float2(a, b));
    return cvt.u;
}

// ---------------------------------------------------------------------------
// wcvt_kernel: one-time fp32 -> bf16 conversion of Wq|Wk|Wv|Wp (RNE, same as
// the in-staging conversion it replaces -> bit-identical downstream).
// ---------------------------------------------------------------------------
__global__ __launch_bounds__(256) void wcvt_kernel(
    const float* __restrict__ Wq, const float* __restrict__ Wk,
    const float* __restrict__ Wv, const float* __restrict__ Wp,
    unsigned short* __restrict__ Wb)
{
    const float* src = (blockIdx.y == 0) ? Wq : (blockIdx.y == 1) ? Wk
                     : (blockIdx.y == 2) ? Wv : Wp;
    unsigned short* dst = Wb + (size_t)blockIdx.y * DIM * DIM;
    const int i = (blockIdx.x * 256 + threadIdx.x) * 8;
    const float4 a0 = *(const float4*)(src + i);
    const float4 a1 = *(const float4*)(src + i + 4);
    union { short8 v; unsigned int u[4]; } t;
    t.u[0] = pk2(a0.x, a0.y); t.u[1] = pk2(a0.z, a0.w);
    t.u[2] = pk2(a1.x, a1.y); t.u[3] = pk2(a1.z, a1.w);
    *(short8*)(dst + i) = t.v;
}

// ---------------------------------------------------------------------------
// qkv_kernel: fused bf16-MFMA projections, 64x128 tiles.  R8: B tile staged
// from pre-converted bf16 weights (1 short8 load, no cvt).
// ---------------------------------------------------------------------------
__global__ __launch_bounds__(256) void qkv_kernel(
    const float* __restrict__ xq, const float* __restrict__ xk, const float* __restrict__ xv,
    const unsigned short* __restrict__ Wb,
    const float* __restrict__ qg, const float* __restrict__ qbeta,
    const float* __restrict__ kg, const float* __restrict__ kbeta,
    unsigned short* __restrict__ Qb, unsigned short* __restrict__ Kb,
    unsigned short* __restrict__ VTb)
{
    __shared__ short8 smem[1536];   // A [0,512)=64x64, B [512,1536)=128x64 (24 KB)
    short8* as = smem;
    short8* bs = smem + 512;
    const int tid  = threadIdx.x;
    const int w    = tid >> 6, lane = tid & 63, m = lane & 15, q = lane >> 4;
    const int wr   = w & 1, wc = w >> 1;
    const int row0 = blockIdx.x * 64;
    const int mat  = blockIdx.y >> 2;
    const int col0 = (blockIdx.y & 3) * 128;
    const float* X = (mat == 0) ? xq : (mat == 1) ? xk : xv;
    const unsigned short* Wm = Wb + (size_t)mat * DIM * DIM;

    floatx4 acc[2][4];
    #pragma unroll
    for (int mt = 0; mt < 2; ++mt)
        #pragma unroll
        for (int nt = 0; nt < 4; ++nt) acc[mt][nt] = (floatx4){0.f, 0.f, 0.f, 0.f};

    for (int k0 = 0; k0 < DIM; k0 += 64) {
        #pragma unroll
        for (int p = 0; p < 6; ++p) {     // 512 A items (fp32+cvt) + 1024 B items (bf16)
            const int idx = tid + p * 256;
            if (idx < 512) {
                const int row = idx >> 3, seg = idx & 7;
                const float4* pa = (const float4*)(X + (size_t)(row0 + row) * DIM + k0 + seg * 8);
                const float4 a0 = pa[0], a1 = pa[1];
                union { short8 v; unsigned int u[4]; } ta;
                ta.u[0] = pk2(a0.x, a0.y); ta.u[1] = pk2(a0.z, a0.w);
                ta.u[2] = pk2(a1.x, a1.y); ta.u[3] = pk2(a1.z, a1.w);
                as[row * 8 + (seg ^ (row & 7))] = ta.v;
            } else {
                const int j = idx - 512;
                const int row = j >> 3, seg = j & 7;
                bs[row * 8 + (seg ^ (row & 7))] =
                    *(const short8*)(Wm + (size_t)(col0 + row) * DIM + k0 + seg * 8);
            }
        }
        __syncthreads();
        #pragma unroll
        for (int s = 0; s < 2; ++s) {
            short8 af[2], bfr[4];
            #pragma unroll
            for (int mt = 0; mt < 2; ++mt)
                af[mt] = as[(wr * 32 + mt * 16 + m) * 8 + ((s * 4 + q) ^ (m & 7))];
            #pragma unroll
            for (int nt = 0; nt < 4; ++nt)
                bfr[nt] = bs[(wc * 64 + nt * 16 + m) * 8 + ((s * 4 + q) ^ (m & 7))];
            #pragma unroll
            for (int mt = 0; mt < 2; ++mt)
                #pragma unroll
                for (int nt = 0; nt < 4; ++nt)
                    acc[mt][nt] = __builtin_amdgcn_mfma_f32_16x16x32_bf16(af[mt], bfr[nt], acc[mt][nt], 0, 0, 0);
        }
        __syncthreads();
    }

    if (mat < 2) {
        const float* g = (mat == 0) ? qg : kg;
        const float* be = (mat == 0) ? qbeta : kbeta;
        unsigned short* Y = (mat == 0) ? Qb : Kb;
        float gv[4], bv[4];
        #pragma unroll
        for (int nt = 0; nt < 4; ++nt) { gv[nt] = g[nt * 16 + m]; bv[nt] = be[nt * 16 + m]; }
        #pragma unroll
        for (int mt = 0; mt < 2; ++mt) {
            #pragma unroll
            for (int r = 0; r < 4; ++r) {
                float s = 0.f, sq = 0.f;
                #pragma unroll
                for (int nt = 0; nt < 4; ++nt) { const float v = acc[mt][nt][r]; s += v; sq += v * v; }
                s  += __shfl_xor(s, 1);  s  += __shfl_xor(s, 2);  s  += __shfl_xor(s, 4);  s  += __shfl_xor(s, 8);
                sq += __shfl_xor(sq, 1); sq += __shfl_xor(sq, 2); sq += __shfl_xor(sq, 4); sq += __shfl_xor(sq, 8);
                const float mean = s * (1.f / HD);
                const float var  = sq * (1.f / HD) - mean * mean;
                const float rr   = rsqrtf(var + EPS);
                const int grow = row0 + wr * 32 + mt * 16 + q * 4 + r;
                #pragma unroll
                for (int nt = 0; nt < 4; ++nt) {
                    float v = (acc[mt][nt][r] - mean) * rr * gv[nt] + bv[nt];
                    if (mat == 0) v *= QSCALE;
                    Y[(size_t)grow * DIM + col0 + wc * 64 + nt * 16 + m] = f2bf(v);
                }
            }
        }
    } else {
        unsigned short* vt = (unsigned short*)smem;
        #pragma unroll
        for (int mt = 0; mt < 2; ++mt)
            #pragma unroll
            for (int nt = 0; nt < 4; ++nt) {
                const int c  = wc * 64 + nt * 16 + m;
                const int rw = wr * 32 + mt * 16 + q * 4;
                *(unsigned int*)(vt + c * 88 + rw)     = pk2(acc[mt][nt][0], acc[mt][nt][1]);
                *(unsigned int*)(vt + c * 88 + rw + 2) = pk2(acc[mt][nt][2], acc[mt][nt][3]);
            }
        __syncthreads();
        #pragma unroll
        for (int p = 0; p < 4; ++p) {
            const int idx = tid + p * 256;      // 1024 items = 128 cols x 8
            const int c = idx >> 3, sg = idx & 7;
            *(short8*)(VTb + (size_t)(col0 + c) * NBANK + row0 + sg * 8) =
                *(const short8*)(vt + c * 88 + sg * 8);
        }
    }
}

// ---------------------------------------------------------------------------
// attn_kernel R8: register-P + prefetch (R7) with mt=2 (32 q-rows/wave,
// 128 q-rows/block) -> kf/vf LDS reads amortized over 2x MFMAs.
// Grid (256, 4).  LDS floor ~26 us, prefetch hides the staging latency.
// ---------------------------------------------------------------------------
__global__ __launch_bounds__(256) void attn_kernel(
    const unsigned short* __restrict__ Qb, const unsigned short* __restrict__ Kb,
    const unsigned short* __restrict__ VTb, unsigned short* __restrict__ AOp,
    float* __restrict__ sums)
{
    __shared__ short8 smem[1024];       // 16 KB: ks [0,512), vts [512,1024)
    short8* ks  = smem;
    short8* vts = smem + 512;
    const int tid  = threadIdx.x;
    const int w    = tid >> 6;               // 0..3
    const int lane = tid & 63;
    const int m    = lane & 15;
    const int Qd   = lane >> 4;
    const int h    = blockIdx.x & 7;
    const int qgi  = blockIdx.x >> 3;        // 0..31
    const int row0 = qgi * 128;
    const int part = blockIdx.y;
    const int base0 = part * 1024;

    // staging assignments (fixed per thread): 2 K items + 2 V items
    const int sn0 = tid >> 3,        sseg = tid & 7;           // item 0
    const int sn1 = (tid + 256) >> 3;                          // item 1 (same seg)
    const unsigned short* kp0 = Kb + (size_t)sn0 * DIM + h * HD + sseg * 8;
    const unsigned short* kp1 = Kb + (size_t)sn1 * DIM + h * HD + sseg * 8;
    const unsigned short* vp0 = VTb + (size_t)(h * HD + sn0) * NBANK + (sseg >> 2) * 32 + (sseg & 3) * 4;
    const unsigned short* vp1 = VTb + (size_t)(h * HD + sn1) * NBANK + (sseg >> 2) * 32 + (sseg & 3) * 4;

    // Q B-operand frags: rows q = row0 + w*32 + mt*16 + m, k = s*32 + Qd*8 + j
    short8 qf[2][2];
    #pragma unroll
    for (int mt = 0; mt < 2; ++mt)
        #pragma unroll
        for (int s = 0; s < 2; ++s)
            qf[mt][s] = *(const short8*)(Qb + (size_t)(row0 + w * 32 + mt * 16 + m) * DIM
                                         + h * HD + s * 32 + Qd * 8);

    floatx4 of[4][2];                    // [d-tile][q-group], O^T
    float sump[2] = {0.f, 0.f};
    #pragma unroll
    for (int t = 0; t < 4; ++t)
        #pragma unroll
        for (int mt = 0; mt < 2; ++mt) of[t][mt] = (floatx4){0.f, 0.f, 0.f, 0.f};

    short8 kreg0, kreg1;
    ushort4 vlo0, vhi0, vlo1, vhi1;

    // prefetch chunk 0
    {
        kreg0 = *(const short8*)(kp0 + (size_t)base0 * DIM);
        kreg1 = *(const short8*)(kp1 + (size_t)base0 * DIM);
        vlo0 = *(const ushort4*)(vp0 + base0);  vhi0 = *(const ushort4*)(vp0 + base0 + 16);
        vlo1 = *(const ushort4*)(vp1 + base0);  vhi1 = *(const ushort4*)(vp1 + base0 + 16);
    }

    for (int c = 0; c < 16; ++c) {
        __syncthreads();                  // prior chunk's LDS reads complete
        // ---- write prefetched regs -> LDS ----
        ks[sn0 * 8 + (sseg ^ (sn0 & 7))] = kreg0;
        ks[sn1 * 8 + (sseg ^ (sn1 & 7))] = kreg1;
        {
            union { short8 v; ushort4 h4[2]; } tv;
            tv.h4[0] = vlo0; tv.h4[1] = vhi0;
            vts[sn0 * 8 + (sseg ^ (sn0 & 7))] = tv.v;
            tv.h4[0] = vlo1; tv.h4[1] = vhi1;
            vts[sn1 * 8 + (sseg ^ (sn1 & 7))] = tv.v;
        }
        __syncthreads();
        // ---- issue next chunk's loads (latency overlaps compute below) ----
        if (c < 15) {
            const int nb = base0 + (c + 1) * 64;
            kreg0 = *(const short8*)(kp0 + (size_t)nb * DIM);
            kreg1 = *(const short8*)(kp1 + (size_t)nb * DIM);
            vlo0 = *(const ushort4*)(vp0 + nb);  vhi0 = *(const ushort4*)(vp0 + nb + 16);
            vlo1 = *(const ushort4*)(vp1 + nb);  vhi1 = *(const ushort4*)(vp1 + nb + 16);
        }

        // ---- S^T = K Q^T : lane holds S[n = t*16 + Qd*4 + r][q = mt*16 + m] ----
        floatx4 st[4][2];
        #pragma unroll
        for (int t = 0; t < 4; ++t)
            #pragma unroll
            for (int mt = 0; mt < 2; ++mt) st[t][mt] = (floatx4){0.f, 0.f, 0.f, 0.f};
        #pragma unroll
        for (int s = 0; s < 2; ++s)
            #pragma unroll
            for (int t = 0; t < 4; ++t) {
                const short8 kf = ks[(t * 16 + m) * 8 + ((s * 4 + Qd) ^ (m & 7))];
                #pragma unroll
                for (int mt = 0; mt < 2; ++mt)
                    st[t][mt] = __builtin_amdgcn_mfma_f32_16x16x32_bf16(kf, qf[mt][s], st[t][mt], 0, 0, 0);
            }

        // ---- P = exp(S^T) in regs; per-lane row-sum partials; pack B-frags ----
        float p[4][2][4];
        #pragma unroll
        for (int t = 0; t < 4; ++t)
            #pragma unroll
            for (int mt = 0; mt < 2; ++mt)
                #pragma unroll
                for (int r = 0; r < 4; ++r) {
                    const float e = __expf(st[t][mt][r]);
                    p[t][mt][r] = e;
                    sump[mt] += e;
                }
        union { short8 v; unsigned int u[4]; } pf[2][2];   // [mt][s2]
        #pragma unroll
        for (int mt = 0; mt < 2; ++mt)
            #pragma unroll
            for (int s2 = 0; s2 < 2; ++s2)
                #pragma unroll
                for (int u = 0; u < 4; ++u)
                    pf[mt][s2].u[u] = pk2(p[s2 * 2 + (u >> 1)][mt][(u & 1) * 2],
                                          p[s2 * 2 + (u >> 1)][mt][(u & 1) * 2 + 1]);

        // ---- O^T += V^T P (bit-permuted V absorbs the layout mismatch) ----
        #pragma unroll
        for (int s2 = 0; s2 < 2; ++s2)
            #pragma unroll
            for (int t2 = 0; t2 < 4; ++t2) {
                const short8 vf = vts[(t2 * 16 + m) * 8 + ((s2 * 4 + Qd) ^ (m & 7))];
                #pragma unroll
                for (int mt = 0; mt < 2; ++mt)
                    of[t2][mt] = __builtin_amdgcn_mfma_f32_16x16x32_bf16(vf, pf[mt][s2].v, of[t2][mt], 0, 0, 0);
            }
    }

    // ---- denominators: reduce per-lane partials across quads ----
    #pragma unroll
    for (int mt = 0; mt < 2; ++mt) {
        float s = sump[mt];
        s += __shfl_xor(s, 16);
        s += __shfl_xor(s, 32);
        sump[mt] = s;                    // total for q = row0 + w*32 + mt*16 + m
    }
    if (Qd == 0) {
        #pragma unroll
        for (int mt = 0; mt < 2; ++mt)
            sums[((size_t)part * NQROWS + row0 + w * 32 + mt * 16 + m) * NHEAD + h] = sump[mt];
    }

    // ---- O^T -> O via LDS (smem dead), coalesced bf16 b128 stores ----
    __syncthreads();
    unsigned int* ob = (unsigned int*)smem;   // O[q 0..127][d/2 0..31] u32
    #pragma unroll
    for (int t2 = 0; t2 < 4; ++t2)
        #pragma unroll
        for (int mt = 0; mt < 2; ++mt) {
            const int q  = w * 32 + mt * 16 + m;
            const int blk = t2 * 2 + (Qd >> 1);            // 16B block in row
            const int sub = (Qd & 1) * 2;
            const int bs  = (blk ^ (q & 7)) * 4;
            ob[q * 32 + bs + sub]     = pk2(of[t2][mt][0], of[t2][mt][1]);
            ob[q * 32 + bs + sub + 1] = pk2(of[t2][mt][2], of[t2][mt][3]);
        }
    __syncthreads();
    #pragma unroll
    for (int pp = 0; pp < 4; ++pp) {
        const int idx = tid + pp * 256;        // 1024 = 128 q x 8 segs
        const int q = idx >> 3, sg = idx & 7;
        *(short8*)(AOp + (size_t)part * PART_ELEMS + (size_t)(row0 + q) * DIM + h * HD + sg * 8) =
            smem[q * 8 + (sg ^ (q & 7))];
    }
}

// ---------------------------------------------------------------------------
// combine_kernel: AO = (sum_p O_p) / (sum_p s_p), bf16 out; fused final-LN
// row stats.  (unchanged R4)
// ---------------------------------------------------------------------------
__global__ __launch_bounds__(256) void combine_kernel(
    const unsigned short* __restrict__ AOp, const float* __restrict__ sums,
    unsigned short* __restrict__ AO, float* __restrict__ meanv, float* __restrict__ rstdv)
{
    __shared__ float rs[256], rq[256];
    const int tid = threadIdx.x;
    const int row = blockIdx.x * 2 + (tid >> 7);
    const int t   = tid & 127;                 // 4 cols per thread
    const int h   = t >> 4;

    float stot = 0.f;
    #pragma unroll
    for (int p = 0; p < 4; ++p)
        stot += sums[((size_t)p * NQROWS + row) * NHEAD + h];

    float o[4] = {0.f, 0.f, 0.f, 0.f};
    #pragma unroll
    for (int p = 0; p < 4; ++p) {
        const ushort4 u = *(const ushort4*)(AOp + (size_t)p * PART_ELEMS + (size_t)row * DIM + t * 4);
        o[0] += bf2f(u.x); o[1] += bf2f(u.y); o[2] += bf2f(u.z); o[3] += bf2f(u.w);
    }
    const float inv = 1.0f / stot;
    float v0 = o[0] * inv, v1 = o[1] * inv, v2 = o[2] * inv, v3 = o[3] * inv;

    uint2 packed;
    packed.x = pk2(v0, v1); packed.y = pk2(v2, v3);
    *(uint2*)(AO + (size_t)row * DIM + t * 4) = packed;

    rs[tid] = v0 + v1 + v2 + v3;
    rq[tid] = v0 * v0 + v1 * v1 + v2 * v2 + v3 * v3;
    __syncthreads();
    #pragma unroll
    for (int off = 64; off > 0; off >>= 1) {
        if (t < off) { rs[tid] += rs[tid + off]; rq[tid] += rq[tid + off]; }
        __syncthreads();
    }
    if (t == 0) {
        const float mean = rs[tid] * (1.f / DIM);
        const float var  = rq[tid] * (1.f / DIM) - mean * mean;
        meanv[row] = mean;
        rstdv[row] = rsqrtf(var + EPS);
    }
}

// ---------------------------------------------------------------------------
// final_kernel: out = LN_512(AO) @ Wproj^T.  R8: W staged from bf16 Wb.
// ---------------------------------------------------------------------------
__global__ __launch_bounds__(256) void final_kernel(
    const unsigned short* __restrict__ AO, const unsigned short* __restrict__ Wpb,
    const float* __restrict__ meanv, const float* __restrict__ rstdv,
    const float* __restrict__ g, const float* __restrict__ be,
    float* __restrict__ out)
{
    __shared__ short8 fs[1024];            // A [0,512)=64x64, B [512,1024)=64x64
    __shared__ float gls[512], bls[512];
    const int tid  = threadIdx.x;
    const int w    = tid >> 6, lane = tid & 63, m = lane & 15, q = lane >> 4;
    const int row0 = blockIdx.x * 64;
    const int col0 = blockIdx.y * 64;

    #pragma unroll
    for (int i = 0; i < 2; ++i) { gls[tid + i * 256] = g[tid + i * 256]; bls[tid + i * 256] = be[tid + i * 256]; }

    floatx4 acc[4];
    #pragma unroll
    for (int mt = 0; mt < 4; ++mt) acc[mt] = (floatx4){0.f, 0.f, 0.f, 0.f};
    __syncthreads();

    for (int k0 = 0; k0 < DIM; k0 += 64) {
        #pragma unroll
        for (int p = 0; p < 4; ++p) {      // 512 A items + 512 B items
            const int idx = tid + p * 256;
            if (idx < 512) {
                const int row = idx >> 3, seg = idx & 7;
                const short8 a = *(const short8*)(AO + (size_t)(row0 + row) * DIM + k0 + seg * 8);
                const float mm = meanv[row0 + row], rr = rstdv[row0 + row];
                const float* gp = gls + k0 + seg * 8;
                const float* bp = bls + k0 + seg * 8;
                float v[8];
                #pragma unroll
                for (int j = 0; j < 8; ++j)
                    v[j] = (bf2f((unsigned short)a[j]) - mm) * rr * gp[j] + bp[j];
                union { short8 s; unsigned int u[4]; } ta;
                ta.u[0] = pk2(v[0], v[1]); ta.u[1] = pk2(v[2], v[3]);
                ta.u[2] = pk2(v[4], v[5]); ta.u[3] = pk2(v[6], v[7]);
                fs[row * 8 + (seg ^ (row & 7))] = ta.s;
            } else {
                const int j = idx - 512;
                const int row = j >> 3, seg = j & 7;
                fs[512 + row * 8 + (seg ^ (row & 7))] =
                    *(const short8*)(Wpb + (size_t)(col0 + row) * DIM + k0 + seg * 8);
            }
        }
        __syncthreads();
        #pragma unroll
        for (int s = 0; s < 2; ++s) {
            short8 af[4];
            #pragma unroll
            for (int mt = 0; mt < 4; ++mt)
                af[mt] = fs[(mt * 16 + m) * 8 + ((s * 4 + q) ^ (m & 7))];
            const short8 bfr = fs[512 + (w * 16 + m) * 8 + ((s * 4 + q) ^ (m & 7))];
            #pragma unroll
            for (int mt = 0; mt < 4; ++mt)
                acc[mt] = __builtin_amdgcn_mfma_f32_16x16x32_bf16(af[mt], bfr, acc[mt], 0, 0, 0);
        }
        __syncthreads();
    }

    #pragma unroll
    for (int mt = 0; mt < 4; ++mt)
        #pragma unroll
        for (int r = 0; r < 4; ++r)
            out[(size_t)(row0 + mt * 16 + q * 4 + r) * DIM + col0 + w * 16 + m] = acc[mt][r];
}

// ---------------------------------------------------------------------------
extern "C" void kernel_launch(void* const* d_in, const int* in_sizes, int n_in,
                              void* d_out, int out_size, void* d_ws, size_t ws_size,
                              hipStream_t stream)
{
    const float* x_q = (const float*)d_in[0];
    const float* x_k = (const float*)d_in[1];
    const float* x_v = (const float*)d_in[2];
    const float* Wq  = (const float*)d_in[3];
    const float* Wk  = (const float*)d_in[4];
    const float* Wv  = (const float*)d_in[5];
    const float* Wp  = (const float*)d_in[6];
    const float* qg  = (const float*)d_in[7];
    const float* qb  = (const float*)d_in[8];
    const float* kg  = (const float*)d_in[9];
    const float* kb  = (const float*)d_in[10];
    const float* ng  = (const float*)d_in[11];
    const float* nb  = (const float*)d_in[12];
    float* out = (float*)d_out;

    // ws: Qb|Kb|VTb (bf16, 4 MB each) | AOp (bf16, 4x4 MB) | sums 512 KB |
    //     stats 32 KB | Wb (bf16 4x512x512 = 2 MB).  Total ~30.6 MB (<= 32 MB
    //     proven in R1).  AO aliases Qb (dead after attn).
    unsigned short* Qb   = (unsigned short*)d_ws;
    unsigned short* Kb   = Qb  + (size_t)NQROWS * DIM;
    unsigned short* VTb  = Kb  + (size_t)NBANK * DIM;
    unsigned short* AOp  = VTb + (size_t)NBANK * DIM;
    float*          sums = (float*)(AOp + (size_t)4 * PART_ELEMS);
    float*          meanv = sums + (size_t)4 * NQROWS * NHEAD;
    float*          rstdv = meanv + NQROWS;
    unsigned short* Wb   = (unsigned short*)(rstdv + NQROWS);
    unsigned short* AO   = Qb;   // alias: Qb dead after attn_kernel

    wcvt_kernel<<<dim3(128, 4), 256, 0, stream>>>(Wq, Wk, Wv, Wp, Wb);
    qkv_kernel<<<dim3(64, 12), 256, 0, stream>>>(x_q, x_k, x_v, Wb,
                                                 qg, qb, kg, kb, Qb, Kb, VTb);
    attn_kernel<<<dim3(256, 4), 256, 0, stream>>>(Qb, Kb, VTb, AOp, sums);
    combine_kernel<<<NQROWS / 2, 256, 0, stream>>>(AOp, sums, AO, meanv, rstdv);
    final_kernel<<<dim3(64, 8), 256, 0, stream>>>(AO, Wb + (size_t)3 * DIM * DIM,
                                                  meanv, rstdv, ng, nb, out);
}

// Round 9
// 171.481 us; speedup vs baseline: 1.4341x; 1.0502x over previous
//
#include <hip/hip_runtime.h>
#include <hip/hip_bf16.h>
#include <math.h>

#define DIM 512
#define NHEAD 8
#define HD 64
#define NBANK 4096
#define NQROWS 4096
#define EPS 1e-5f
#define QSCALE 0.125f
#define PART_ELEMS (NQROWS * DIM)   // one O-partial buffer (bf16 elems)

typedef __attribute__((ext_vector_type(4))) float floatx4;
typedef __attribute__((ext_vector_type(8))) short short8;

__device__ __forceinline__ unsigned short f2bf(float f) {
    unsigned int u = __float_as_uint(f);
    u += 0x7fffu + ((u >> 16) & 1u);          // round-to-nearest-even
    return (unsigned short)(u >> 16);
}
__device__ __forceinline__ float bf2f(unsigned short h) {
    return __uint_as_float(((unsigned int)h) << 16);
}
// packed fp32x2 -> bf16x2 (v_cvt_pk_bf16_f32), low short = a
__device__ __forceinline__ unsigned int pk2(float a, float b) {
    union { __hip_bfloat162 h; unsigned int u; } cvt;
    cvt.h = __float22bfloat162_rn(make_float2(a, b));
    return cvt.u;
}

// ---------------------------------------------------------------------------
// wcvt_kernel: one-time fp32 -> bf16 conversion of Wq|Wk|Wv|Wp.
// ---------------------------------------------------------------------------
__global__ __launch_bounds__(256) void wcvt_kernel(
    const float* __restrict__ Wq, const float* __restrict__ Wk,
    const float* __restrict__ Wv, const float* __restrict__ Wp,
    unsigned short* __restrict__ Wb)
{
    const float* src = (blockIdx.y == 0) ? Wq : (blockIdx.y == 1) ? Wk
                     : (blockIdx.y == 2) ? Wv : Wp;
    unsigned short* dst = Wb + (size_t)blockIdx.y * DIM * DIM;
    const int i = (blockIdx.x * 256 + threadIdx.x) * 8;
    const float4 a0 = *(const float4*)(src + i);
    const float4 a1 = *(const float4*)(src + i + 4);
    union { short8 v; unsigned int u[4]; } t;
    t.u[0] = pk2(a0.x, a0.y); t.u[1] = pk2(a0.z, a0.w);
    t.u[2] = pk2(a1.x, a1.y); t.u[3] = pk2(a1.z, a1.w);
    *(short8*)(dst + i) = t.v;
}

// ---------------------------------------------------------------------------
// qkv_kernel R9: 64x128 tiles, LDS ping-pong + register prefetch, ONE barrier
// per k-iter.  Buf p at smem + p*1536 (A 512 + B 1024); 48 KB total.
// ---------------------------------------------------------------------------
__global__ __launch_bounds__(256) void qkv_kernel(
    const float* __restrict__ xq, const float* __restrict__ xk, const float* __restrict__ xv,
    const unsigned short* __restrict__ Wb,
    const float* __restrict__ qg, const float* __restrict__ qbeta,
    const float* __restrict__ kg, const float* __restrict__ kbeta,
    unsigned short* __restrict__ Qb, unsigned short* __restrict__ Kb,
    unsigned short* __restrict__ VTb)
{
    __shared__ short8 smem[3072];   // 48 KB: buf p = smem + p*1536 (A 512 | B 1024)
    const int tid  = threadIdx.x;
    const int w    = tid >> 6, lane = tid & 63, m = lane & 15, q = lane >> 4;
    const int wr   = w & 1, wc = w >> 1;
    const int row0 = blockIdx.x * 64;
    const int mat  = blockIdx.y >> 2;
    const int col0 = (blockIdx.y & 3) * 128;
    const float* X = (mat == 0) ? xq : (mat == 1) ? xk : xv;
    const unsigned short* Wm = Wb + (size_t)mat * DIM * DIM;

    // fixed per-thread staging assignments
    const int arow0 = tid >> 3,           aseg = tid & 7;           // A item 0
    const int arow1 = (tid + 256) >> 3;                             // A item 1
    const float* ap0 = X + (size_t)(row0 + arow0) * DIM + aseg * 8;
    const float* ap1 = X + (size_t)(row0 + arow1) * DIM + aseg * 8;
    const int adst0 = arow0 * 8 + (aseg ^ (arow0 & 7));
    const int adst1 = arow1 * 8 + (aseg ^ (arow1 & 7));
    int brow[4], bdst[4];
    const unsigned short* bp[4];
    #pragma unroll
    for (int j = 0; j < 4; ++j) {
        const int idx = tid + j * 256;
        brow[j] = idx >> 3; const int seg = idx & 7;
        bp[j] = Wm + (size_t)(col0 + brow[j]) * DIM + seg * 8;
        bdst[j] = brow[j] * 8 + (seg ^ (brow[j] & 7));
    }

    floatx4 acc[2][4];
    #pragma unroll
    for (int mt = 0; mt < 2; ++mt)
        #pragma unroll
        for (int nt = 0; nt < 4; ++nt) acc[mt][nt] = (floatx4){0.f, 0.f, 0.f, 0.f};

    float4 pa[4];        // A prefetch (2 items x 2 float4)
    short8 pb[4];        // B prefetch

    // prefetch tile 0
    pa[0] = *(const float4*)(ap0);     pa[1] = *(const float4*)(ap0 + 4);
    pa[2] = *(const float4*)(ap1);     pa[3] = *(const float4*)(ap1 + 4);
    #pragma unroll
    for (int j = 0; j < 4; ++j) pb[j] = *(const short8*)(bp[j]);
    // write tile 0 -> buf0
    {
        short8* as = smem; short8* bs = smem + 512;
        union { short8 v; unsigned int u[4]; } ta;
        ta.u[0] = pk2(pa[0].x, pa[0].y); ta.u[1] = pk2(pa[0].z, pa[0].w);
        ta.u[2] = pk2(pa[1].x, pa[1].y); ta.u[3] = pk2(pa[1].z, pa[1].w);
        as[adst0] = ta.v;
        ta.u[0] = pk2(pa[2].x, pa[2].y); ta.u[1] = pk2(pa[2].z, pa[2].w);
        ta.u[2] = pk2(pa[3].x, pa[3].y); ta.u[3] = pk2(pa[3].z, pa[3].w);
        as[adst1] = ta.v;
        #pragma unroll
        for (int j = 0; j < 4; ++j) bs[bdst[j]] = pb[j];
    }
    // prefetch tile 1
    pa[0] = *(const float4*)(ap0 + 64);  pa[1] = *(const float4*)(ap0 + 68);
    pa[2] = *(const float4*)(ap1 + 64);  pa[3] = *(const float4*)(ap1 + 68);
    #pragma unroll
    for (int j = 0; j < 4; ++j) pb[j] = *(const short8*)(bp[j] + 64);
    __syncthreads();

    for (int kt = 0; kt < 8; ++kt) {
        short8* as  = smem + (kt & 1) * 1536;
        short8* bs  = as + 512;
        short8* asn = smem + ((kt + 1) & 1) * 1536;
        short8* bsn = asn + 512;
        if (kt < 7) {              // write prefetched tile kt+1 -> other buf
            union { short8 v; unsigned int u[4]; } ta;
            ta.u[0] = pk2(pa[0].x, pa[0].y); ta.u[1] = pk2(pa[0].z, pa[0].w);
            ta.u[2] = pk2(pa[1].x, pa[1].y); ta.u[3] = pk2(pa[1].z, pa[1].w);
            asn[adst0] = ta.v;
            ta.u[0] = pk2(pa[2].x, pa[2].y); ta.u[1] = pk2(pa[2].z, pa[2].w);
            ta.u[2] = pk2(pa[3].x, pa[3].y); ta.u[3] = pk2(pa[3].z, pa[3].w);
            asn[adst1] = ta.v;
            #pragma unroll
            for (int j = 0; j < 4; ++j) bsn[bdst[j]] = pb[j];
        }
        if (kt < 6) {              // prefetch tile kt+2
            const int o = (kt + 2) * 64;
            pa[0] = *(const float4*)(ap0 + o);  pa[1] = *(const float4*)(ap0 + o + 4);
            pa[2] = *(const float4*)(ap1 + o);  pa[3] = *(const float4*)(ap1 + o + 4);
            #pragma unroll
            for (int j = 0; j < 4; ++j) pb[j] = *(const short8*)(bp[j] + o);
        }
        #pragma unroll
        for (int s = 0; s < 2; ++s) {
            short8 af[2], bfr[4];
            #pragma unroll
            for (int mt = 0; mt < 2; ++mt)
                af[mt] = as[(wr * 32 + mt * 16 + m) * 8 + ((s * 4 + q) ^ (m & 7))];
            #pragma unroll
            for (int nt = 0; nt < 4; ++nt)
                bfr[nt] = bs[(wc * 64 + nt * 16 + m) * 8 + ((s * 4 + q) ^ (m & 7))];
            #pragma unroll
            for (int mt = 0; mt < 2; ++mt)
                #pragma unroll
                for (int nt = 0; nt < 4; ++nt)
                    acc[mt][nt] = __builtin_amdgcn_mfma_f32_16x16x32_bf16(af[mt], bfr[nt], acc[mt][nt], 0, 0, 0);
        }
        __syncthreads();
    }

    if (mat < 2) {
        const float* g = (mat == 0) ? qg : kg;
        const float* be = (mat == 0) ? qbeta : kbeta;
        unsigned short* Y = (mat == 0) ? Qb : Kb;
        float gv[4], bv[4];
        #pragma unroll
        for (int nt = 0; nt < 4; ++nt) { gv[nt] = g[nt * 16 + m]; bv[nt] = be[nt * 16 + m]; }
        #pragma unroll
        for (int mt = 0; mt < 2; ++mt) {
            #pragma unroll
            for (int r = 0; r < 4; ++r) {
                float s = 0.f, sq = 0.f;
                #pragma unroll
                for (int nt = 0; nt < 4; ++nt) { const float v = acc[mt][nt][r]; s += v; sq += v * v; }
                s  += __shfl_xor(s, 1);  s  += __shfl_xor(s, 2);  s  += __shfl_xor(s, 4);  s  += __shfl_xor(s, 8);
                sq += __shfl_xor(sq, 1); sq += __shfl_xor(sq, 2); sq += __shfl_xor(sq, 4); sq += __shfl_xor(sq, 8);
                const float mean = s * (1.f / HD);
                const float var  = sq * (1.f / HD) - mean * mean;
                const float rr   = rsqrtf(var + EPS);
                const int grow = row0 + wr * 32 + mt * 16 + q * 4 + r;
                #pragma unroll
                for (int nt = 0; nt < 4; ++nt) {
                    float v = (acc[mt][nt][r] - mean) * rr * gv[nt] + bv[nt];
                    if (mat == 0) v *= QSCALE;
                    Y[(size_t)grow * DIM + col0 + wc * 64 + nt * 16 + m] = f2bf(v);
                }
            }
        }
    } else {
        unsigned short* vt = (unsigned short*)smem;
        #pragma unroll
        for (int mt = 0; mt < 2; ++mt)
            #pragma unroll
            for (int nt = 0; nt < 4; ++nt) {
                const int c  = wc * 64 + nt * 16 + m;
                const int rw = wr * 32 + mt * 16 + q * 4;
                *(unsigned int*)(vt + c * 88 + rw)     = pk2(acc[mt][nt][0], acc[mt][nt][1]);
                *(unsigned int*)(vt + c * 88 + rw + 2) = pk2(acc[mt][nt][2], acc[mt][nt][3]);
            }
        __syncthreads();
        #pragma unroll
        for (int p = 0; p < 4; ++p) {
            const int idx = tid + p * 256;      // 1024 items = 128 cols x 8
            const int c = idx >> 3, sg = idx & 7;
            *(short8*)(VTb + (size_t)(col0 + c) * NBANK + row0 + sg * 8) =
                *(const short8*)(vt + c * 88 + sg * 8);
        }
    }
}

// ---------------------------------------------------------------------------
// attn_kernel R9: register-P + prefetch + LDS PING-PONG (one barrier/chunk).
// mt=2 (128 q-rows/block), grid (256,4).  Buf p = smem + p*1024; 32 KB.
// ---------------------------------------------------------------------------
__global__ __launch_bounds__(256) void attn_kernel(
    const unsigned short* __restrict__ Qb, const unsigned short* __restrict__ Kb,
    const unsigned short* __restrict__ VTb, unsigned short* __restrict__ AOp,
    float* __restrict__ sums)
{
    __shared__ short8 smem[2048];       // 32 KB: buf p: ks = +p*1024, vts = +p*1024+512
    const int tid  = threadIdx.x;
    const int w    = tid >> 6;
    const int lane = tid & 63;
    const int m    = lane & 15;
    const int Qd   = lane >> 4;
    const int h    = blockIdx.x & 7;
    const int qgi  = blockIdx.x >> 3;        // 0..31
    const int row0 = qgi * 128;
    const int part = blockIdx.y;
    const int base0 = part * 1024;

    // staging assignments (fixed per thread): 2 K items + 2 V items
    const int sn0 = tid >> 3,        sseg = tid & 7;
    const int sn1 = (tid + 256) >> 3;
    const int kd0 = sn0 * 8 + (sseg ^ (sn0 & 7));
    const int kd1 = sn1 * 8 + (sseg ^ (sn1 & 7));
    const unsigned short* kp0 = Kb + (size_t)sn0 * DIM + h * HD + sseg * 8;
    const unsigned short* kp1 = Kb + (size_t)sn1 * DIM + h * HD + sseg * 8;
    const unsigned short* vp0 = VTb + (size_t)(h * HD + sn0) * NBANK + (sseg >> 2) * 32 + (sseg & 3) * 4;
    const unsigned short* vp1 = VTb + (size_t)(h * HD + sn1) * NBANK + (sseg >> 2) * 32 + (sseg & 3) * 4;

    short8 qf[2][2];
    #pragma unroll
    for (int mt = 0; mt < 2; ++mt)
        #pragma unroll
        for (int s = 0; s < 2; ++s)
            qf[mt][s] = *(const short8*)(Qb + (size_t)(row0 + w * 32 + mt * 16 + m) * DIM
                                         + h * HD + s * 32 + Qd * 8);

    floatx4 of[4][2];
    float sump[2] = {0.f, 0.f};
    #pragma unroll
    for (int t = 0; t < 4; ++t)
        #pragma unroll
        for (int mt = 0; mt < 2; ++mt) of[t][mt] = (floatx4){0.f, 0.f, 0.f, 0.f};

    short8 kreg0, kreg1;
    ushort4 vlo0, vhi0, vlo1, vhi1;

    // prefetch chunk 0 and write -> buf0
    kreg0 = *(const short8*)(kp0 + (size_t)base0 * DIM);
    kreg1 = *(const short8*)(kp1 + (size_t)base0 * DIM);
    vlo0 = *(const ushort4*)(vp0 + base0);  vhi0 = *(const ushort4*)(vp0 + base0 + 16);
    vlo1 = *(const ushort4*)(vp1 + base0);  vhi1 = *(const ushort4*)(vp1 + base0 + 16);
    {
        short8* ks = smem; short8* vts = smem + 512;
        ks[kd0] = kreg0; ks[kd1] = kreg1;
        union { short8 v; ushort4 h4[2]; } tv;
        tv.h4[0] = vlo0; tv.h4[1] = vhi0;  vts[kd0] = tv.v;
        tv.h4[0] = vlo1; tv.h4[1] = vhi1;  vts[kd1] = tv.v;
    }
    // prefetch chunk 1
    kreg0 = *(const short8*)(kp0 + (size_t)(base0 + 64) * DIM);
    kreg1 = *(const short8*)(kp1 + (size_t)(base0 + 64) * DIM);
    vlo0 = *(const ushort4*)(vp0 + base0 + 64);  vhi0 = *(const ushort4*)(vp0 + base0 + 80);
    vlo1 = *(const ushort4*)(vp1 + base0 + 64);  vhi1 = *(const ushort4*)(vp1 + base0 + 80);
    __syncthreads();

    for (int c = 0; c < 16; ++c) {
        short8* ks   = smem + (c & 1) * 1024;
        short8* vts  = ks + 512;
        short8* ksn  = smem + ((c + 1) & 1) * 1024;
        short8* vtsn = ksn + 512;
        if (c < 15) {             // write prefetched chunk c+1 -> other buf
            ksn[kd0] = kreg0; ksn[kd1] = kreg1;
            union { short8 v; ushort4 h4[2]; } tv;
            tv.h4[0] = vlo0; tv.h4[1] = vhi0;  vtsn[kd0] = tv.v;
            tv.h4[0] = vlo1; tv.h4[1] = vhi1;  vtsn[kd1] = tv.v;
        }
        if (c < 14) {             // prefetch chunk c+2
            const int nb = base0 + (c + 2) * 64;
            kreg0 = *(const short8*)(kp0 + (size_t)nb * DIM);
            kreg1 = *(const short8*)(kp1 + (size_t)nb * DIM);
            vlo0 = *(const ushort4*)(vp0 + nb);  vhi0 = *(const ushort4*)(vp0 + nb + 16);
            vlo1 = *(const ushort4*)(vp1 + nb);  vhi1 = *(const ushort4*)(vp1 + nb + 16);
        }

        // ---- S^T = K Q^T ----
        floatx4 st[4][2];
        #pragma unroll
        for (int t = 0; t < 4; ++t)
            #pragma unroll
            for (int mt = 0; mt < 2; ++mt) st[t][mt] = (floatx4){0.f, 0.f, 0.f, 0.f};
        #pragma unroll
        for (int s = 0; s < 2; ++s)
            #pragma unroll
            for (int t = 0; t < 4; ++t) {
                const short8 kf = ks[(t * 16 + m) * 8 + ((s * 4 + Qd) ^ (m & 7))];
                #pragma unroll
                for (int mt = 0; mt < 2; ++mt)
                    st[t][mt] = __builtin_amdgcn_mfma_f32_16x16x32_bf16(kf, qf[mt][s], st[t][mt], 0, 0, 0);
            }

        // ---- P = exp(S^T); row-sum partials; pack B-frags ----
        float p[4][2][4];
        #pragma unroll
        for (int t = 0; t < 4; ++t)
            #pragma unroll
            for (int mt = 0; mt < 2; ++mt)
                #pragma unroll
                for (int r = 0; r < 4; ++r) {
                    const float e = __expf(st[t][mt][r]);
                    p[t][mt][r] = e;
                    sump[mt] += e;
                }
        union { short8 v; unsigned int u[4]; } pf[2][2];
        #pragma unroll
        for (int mt = 0; mt < 2; ++mt)
            #pragma unroll
            for (int s2 = 0; s2 < 2; ++s2)
                #pragma unroll
                for (int u = 0; u < 4; ++u)
                    pf[mt][s2].u[u] = pk2(p[s2 * 2 + (u >> 1)][mt][(u & 1) * 2],
                                          p[s2 * 2 + (u >> 1)][mt][(u & 1) * 2 + 1]);

        // ---- O^T += V^T P ----
        #pragma unroll
        for (int s2 = 0; s2 < 2; ++s2)
            #pragma unroll
            for (int t2 = 0; t2 < 4; ++t2) {
                const short8 vf = vts[(t2 * 16 + m) * 8 + ((s2 * 4 + Qd) ^ (m & 7))];
                #pragma unroll
                for (int mt = 0; mt < 2; ++mt)
                    of[t2][mt] = __builtin_amdgcn_mfma_f32_16x16x32_bf16(vf, pf[mt][s2].v, of[t2][mt], 0, 0, 0);
            }
        __syncthreads();
    }

    // ---- denominators ----
    #pragma unroll
    for (int mt = 0; mt < 2; ++mt) {
        float s = sump[mt];
        s += __shfl_xor(s, 16);
        s += __shfl_xor(s, 32);
        sump[mt] = s;
    }
    if (Qd == 0) {
        #pragma unroll
        for (int mt = 0; mt < 2; ++mt)
            sums[((size_t)part * NQROWS + row0 + w * 32 + mt * 16 + m) * NHEAD + h] = sump[mt];
    }

    // ---- O^T -> O via LDS, coalesced bf16 b128 stores ----
    unsigned int* ob = (unsigned int*)smem;
    #pragma unroll
    for (int t2 = 0; t2 < 4; ++t2)
        #pragma unroll
        for (int mt = 0; mt < 2; ++mt) {
            const int q  = w * 32 + mt * 16 + m;
            const int blk = t2 * 2 + (Qd >> 1);
            const int sub = (Qd & 1) * 2;
            const int bs  = (blk ^ (q & 7)) * 4;
            ob[q * 32 + bs + sub]     = pk2(of[t2][mt][0], of[t2][mt][1]);
            ob[q * 32 + bs + sub + 1] = pk2(of[t2][mt][2], of[t2][mt][3]);
        }
    __syncthreads();
    #pragma unroll
    for (int pp = 0; pp < 4; ++pp) {
        const int idx = tid + pp * 256;
        const int q = idx >> 3, sg = idx & 7;
        *(short8*)(AOp + (size_t)part * PART_ELEMS + (size_t)(row0 + q) * DIM + h * HD + sg * 8) =
            smem[q * 8 + (sg ^ (q & 7))];
    }
}

// ---------------------------------------------------------------------------
// combine_kernel R9: AO = LN_512( (sum_p O_p) / (sum_p s_p) ) as bf16.
// Final LN fully applied here (stats + normalize in-register).
// ---------------------------------------------------------------------------
__global__ __launch_bounds__(256) void combine_kernel(
    const unsigned short* __restrict__ AOp, const float* __restrict__ sums,
    const float* __restrict__ g, const float* __restrict__ be,
    unsigned short* __restrict__ AO)
{
    __shared__ float rs[256], rq[256], sm[2], sr[2];
    const int tid  = threadIdx.x;
    const int half = tid >> 7;
    const int row  = blockIdx.x * 2 + half;
    const int t    = tid & 127;                 // 4 cols per thread
    const int h    = t >> 4;

    float stot = 0.f;
    #pragma unroll
    for (int p = 0; p < 4; ++p)
        stot += sums[((size_t)p * NQROWS + row) * NHEAD + h];

    float o[4] = {0.f, 0.f, 0.f, 0.f};
    #pragma unroll
    for (int p = 0; p < 4; ++p) {
        const ushort4 u = *(const ushort4*)(AOp + (size_t)p * PART_ELEMS + (size_t)row * DIM + t * 4);
        o[0] += bf2f(u.x); o[1] += bf2f(u.y); o[2] += bf2f(u.z); o[3] += bf2f(u.w);
    }
    const float inv = 1.0f / stot;
    const float v0 = o[0] * inv, v1 = o[1] * inv, v2 = o[2] * inv, v3 = o[3] * inv;

    rs[tid] = v0 + v1 + v2 + v3;
    rq[tid] = v0 * v0 + v1 * v1 + v2 * v2 + v3 * v3;
    __syncthreads();
    #pragma unroll
    for (int off = 64; off > 0; off >>= 1) {
        if (t < off) { rs[tid] += rs[tid + off]; rq[tid] += rq[tid + off]; }
        __syncthreads();
    }
    if (t == 0) {
        const float mean = rs[tid] * (1.f / DIM);
        const float var  = rq[tid] * (1.f / DIM) - mean * mean;
        sm[half] = mean;
        sr[half] = rsqrtf(var + EPS);
    }
    __syncthreads();

    const float mean = sm[half], rstd = sr[half];
    const float4 g4 = *(const float4*)(g + t * 4);
    const float4 b4 = *(const float4*)(be + t * 4);
    uint2 packed;
    packed.x = pk2((v0 - mean) * rstd * g4.x + b4.x, (v1 - mean) * rstd * g4.y + b4.y);
    packed.y = pk2((v2 - mean) * rstd * g4.z + b4.z, (v3 - mean) * rstd * g4.w + b4.w);
    *(uint2*)(AO + (size_t)row * DIM + t * 4) = packed;
}

// ---------------------------------------------------------------------------
// final_kernel R9: pure bf16 GEMM out = AO @ Wproj^T (LN already in AO).
// 64x64 tiles, ping-pong + register prefetch, one barrier per k-iter. 32 KB.
// ---------------------------------------------------------------------------
__global__ __launch_bounds__(256) void final_kernel(
    const unsigned short* __restrict__ AO, const unsigned short* __restrict__ Wpb,
    float* __restrict__ out)
{
    __shared__ short8 fs[2048];            // buf p = fs + p*1024 (A 512 | B 512)
    const int tid  = threadIdx.x;
    const int w    = tid >> 6, lane = tid & 63, m = lane & 15, q = lane >> 4;
    const int row0 = blockIdx.x * 64;
    const int col0 = blockIdx.y * 64;

    // per-thread staging: 2 A items + 2 B items
    const int r0 = tid >> 3,           sseg = tid & 7;
    const int r1 = (tid + 256) >> 3;
    const int d0 = r0 * 8 + (sseg ^ (r0 & 7));
    const int d1 = r1 * 8 + (sseg ^ (r1 & 7));
    const unsigned short* ap0 = AO  + (size_t)(row0 + r0) * DIM + sseg * 8;
    const unsigned short* ap1 = AO  + (size_t)(row0 + r1) * DIM + sseg * 8;
    const unsigned short* wp0 = Wpb + (size_t)(col0 + r0) * DIM + sseg * 8;
    const unsigned short* wp1 = Wpb + (size_t)(col0 + r1) * DIM + sseg * 8;

    floatx4 acc[4];
    #pragma unroll
    for (int mt = 0; mt < 4; ++mt) acc[mt] = (floatx4){0.f, 0.f, 0.f, 0.f};

    short8 pa0, pa1, pw0, pw1;
    pa0 = *(const short8*)(ap0);       pa1 = *(const short8*)(ap1);
    pw0 = *(const short8*)(wp0);       pw1 = *(const short8*)(wp1);
    {
        fs[d0] = pa0; fs[d1] = pa1;
        fs[512 + d0] = pw0; fs[512 + d1] = pw1;
    }
    pa0 = *(const short8*)(ap0 + 64);  pa1 = *(const short8*)(ap1 + 64);
    pw0 = *(const short8*)(wp0 + 64);  pw1 = *(const short8*)(wp1 + 64);
    __syncthreads();

    for (int kt = 0; kt < 8; ++kt) {
        short8* buf  = fs + (kt & 1) * 1024;
        short8* bufn = fs + ((kt + 1) & 1) * 1024;
        if (kt < 7) {
            bufn[d0] = pa0; bufn[d1] = pa1;
            bufn[512 + d0] = pw0; bufn[512 + d1] = pw1;
        }
        if (kt < 6) {
            const int o = (kt + 2) * 64;
            pa0 = *(const short8*)(ap0 + o);  pa1 = *(const short8*)(ap1 + o);
            pw0 = *(const short8*)(wp0 + o);  pw1 = *(const short8*)(wp1 + o);
        }
        #pragma unroll
        for (int s = 0; s < 2; ++s) {
            short8 af[4];
            #pragma unroll
            for (int mt = 0; mt < 4; ++mt)
                af[mt] = buf[(mt * 16 + m) * 8 + ((s * 4 + q) ^ (m & 7))];
            const short8 bfr = buf[512 + (w * 16 + m) * 8 + ((s * 4 + q) ^ (m & 7))];
            #pragma unroll
            for (int mt = 0; mt < 4; ++mt)
                acc[mt] = __builtin_amdgcn_mfma_f32_16x16x32_bf16(af[mt], bfr, acc[mt], 0, 0, 0);
        }
        __syncthreads();
    }

    #pragma unroll
    for (int mt = 0; mt < 4; ++mt)
        #pragma unroll
        for (int r = 0; r < 4; ++r)
            out[(size_t)(row0 + mt * 16 + q * 4 + r) * DIM + col0 + w * 16 + m] = acc[mt][r];
}

// ---------------------------------------------------------------------------
extern "C" void kernel_launch(void* const* d_in, const int* in_sizes, int n_in,
                              void* d_out, int out_size, void* d_ws, size_t ws_size,
                              hipStream_t stream)
{
    const float* x_q = (const float*)d_in[0];
    const float* x_k = (const float*)d_in[1];
    const float* x_v = (const float*)d_in[2];
    const float* Wq  = (const float*)d_in[3];
    const float* Wk  = (const float*)d_in[4];
    const float* Wv  = (const float*)d_in[5];
    const float* Wp  = (const float*)d_in[6];
    const float* qg  = (const float*)d_in[7];
    const float* qb  = (const float*)d_in[8];
    const float* kg  = (const float*)d_in[9];
    const float* kb  = (const float*)d_in[10];
    const float* ng  = (const float*)d_in[11];
    const float* nb  = (const float*)d_in[12];
    float* out = (float*)d_out;

    // ws: Qb|Kb|VTb (bf16, 4 MB each) | AOp (4x4 MB) | sums 512 KB | Wb 2 MB.
    unsigned short* Qb   = (unsigned short*)d_ws;
    unsigned short* Kb   = Qb  + (size_t)NQROWS * DIM;
    unsigned short* VTb  = Kb  + (size_t)NBANK * DIM;
    unsigned short* AOp  = VTb + (size_t)NBANK * DIM;
    float*          sums = (float*)(AOp + (size_t)4 * PART_ELEMS);
    unsigned short* Wb   = (unsigned short*)(sums + (size_t)4 * NQROWS * NHEAD);
    unsigned short* AO   = Qb;   // alias: Qb dead after attn_kernel

    wcvt_kernel<<<dim3(128, 4), 256, 0, stream>>>(Wq, Wk, Wv, Wp, Wb);
    qkv_kernel<<<dim3(64, 12), 256, 0, stream>>>(x_q, x_k, x_v, Wb,
                                                 qg, qb, kg, kb, Qb, Kb, VTb);
    attn_kernel<<<dim3(256, 4), 256, 0, stream>>>(Qb, Kb, VTb, AOp, sums);
    combine_kernel<<<NQROWS / 2, 256, 0, stream>>>(AOp, sums, ng, nb, AO);
    final_kernel<<<dim3(64, 8), 256, 0, stream>>>(AO, Wb + (size_t)3 * DIM * DIM, out);
}

// Round 10
// 170.246 us; speedup vs baseline: 1.4445x; 1.0073x over previous
//
#include <hip/hip_runtime.h>
#include <hip/hip_bf16.h>
#include <math.h>

#define DIM 512
#define NHEAD 8
#define HD 64
#define NBANK 4096
#define NQROWS 4096
#define EPS 1e-5f
#define QSCALE 0.125f
#define PART_ELEMS (NQROWS * DIM)   // one O-partial buffer (bf16 elems)

typedef __attribute__((ext_vector_type(4))) float floatx4;
typedef __attribute__((ext_vector_type(8))) short short8;

__device__ __forceinline__ unsigned short f2bf(float f) {
    unsigned int u = __float_as_uint(f);
    u += 0x7fffu + ((u >> 16) & 1u);          // round-to-nearest-even
    return (unsigned short)(u >> 16);
}
__device__ __forceinline__ float bf2f(unsigned short h) {
    return __uint_as_float(((unsigned int)h) << 16);
}
// packed fp32x2 -> bf16x2 (v_cvt_pk_bf16_f32), low short = a
__device__ __forceinline__ unsigned int pk2(float a, float b) {
    union { __hip_bfloat162 h; unsigned int u; } cvt;
    cvt.h = __float22bfloat162_rn(make_float2(a, b));
    return cvt.u;
}
// async 16B global -> LDS DMA (global_load_lds_dwordx4).  gsrc per-lane,
// ldst wave-uniform slab base; HW adds lane*16.
__device__ __forceinline__ void dma16(const void* gsrc, void* ldst) {
    __builtin_amdgcn_global_load_lds(
        (const __attribute__((address_space(1))) unsigned int*)gsrc,
        (__attribute__((address_space(3))) unsigned int*)ldst, 16, 0, 0);
}

// ---------------------------------------------------------------------------
// wcvt_kernel: fp32 -> bf16 W, stored SEG-SWIZZLED per 64-elem k-tile:
// Wb[row][kt][seg^(row&7)] = W[row][kt*64+seg*8 ..8]  -> consumers DMA linearly.
// ---------------------------------------------------------------------------
__global__ __launch_bounds__(256) void wcvt_kernel(
    const float* __restrict__ Wq, const float* __restrict__ Wk,
    const float* __restrict__ Wv, const float* __restrict__ Wp,
    unsigned short* __restrict__ Wb)
{
    const float* src = (blockIdx.y == 0) ? Wq : (blockIdx.y == 1) ? Wk
                     : (blockIdx.y == 2) ? Wv : Wp;
    unsigned short* dst = Wb + (size_t)blockIdx.y * DIM * DIM;
    const int i = (blockIdx.x * 256 + threadIdx.x) * 8;
    const int row = i >> 9, kpos = i & 511;
    const int kt = kpos >> 6, seg = (kpos >> 3) & 7;
    const float4 a0 = *(const float4*)(src + i);
    const float4 a1 = *(const float4*)(src + i + 4);
    union { short8 v; unsigned int u[4]; } t;
    t.u[0] = pk2(a0.x, a0.y); t.u[1] = pk2(a0.z, a0.w);
    t.u[2] = pk2(a1.x, a1.y); t.u[3] = pk2(a1.z, a1.w);
    *(short8*)(dst + (size_t)row * 512 + kt * 64 + ((seg ^ (row & 7)) << 3)) = t.v;
}

// ---------------------------------------------------------------------------
// qkv_kernel R10: 64x128 tiles, ping-pong, one barrier/k-iter.
// A (fp32 x) staged via register prefetch + cvt; B (bf16 W, pre-swizzled)
// staged via global_load_lds DMA.  Epilogues write ATTN-READY layouts:
//   Q natural | K seg-swizzled per row | V chunk-packed VTb_new.
// ---------------------------------------------------------------------------
__global__ __launch_bounds__(256) void qkv_kernel(
    const float* __restrict__ xq, const float* __restrict__ xk, const float* __restrict__ xv,
    const unsigned short* __restrict__ Wb,
    const float* __restrict__ qg, const float* __restrict__ qbeta,
    const float* __restrict__ kg, const float* __restrict__ kbeta,
    unsigned short* __restrict__ Qb, unsigned short* __restrict__ Kb,
    unsigned short* __restrict__ VTb)
{
    __shared__ short8 smem[3072];   // 48 KB: buf p = smem + p*1536 (A 512 | B 1024)
    const int tid  = threadIdx.x;
    const int w    = tid >> 6, lane = tid & 63, m = lane & 15, q = lane >> 4;
    const int wr   = w & 1, wc = w >> 1;
    const int row0 = blockIdx.x * 64;
    const int mat  = blockIdx.y >> 2;
    const int col0 = (blockIdx.y & 3) * 128;
    const float* X = (mat == 0) ? xq : (mat == 1) ? xk : xv;
    const unsigned short* Wm = Wb + (size_t)mat * DIM * DIM;

    // A staging (manual): 2 items/thread
    const int arow0 = tid >> 3,           aseg = tid & 7;
    const int arow1 = (tid + 256) >> 3;
    const float* ap0 = X + (size_t)(row0 + arow0) * DIM + aseg * 8;
    const float* ap1 = X + (size_t)(row0 + arow1) * DIM + aseg * 8;
    const int adst0 = arow0 * 8 + (aseg ^ (arow0 & 7));
    const int adst1 = arow1 * 8 + (aseg ^ (arow1 & 7));
    // B DMA: per j, item = j*256 + tid; per-lane src, wave-uniform dest slab
    const unsigned short* bsrc[4];
    #pragma unroll
    for (int j = 0; j < 4; ++j) {
        const int item = j * 256 + tid;
        bsrc[j] = Wm + (size_t)(col0 + (item >> 3)) * DIM + (item & 7) * 8;
    }

    floatx4 acc[2][4];
    #pragma unroll
    for (int mt = 0; mt < 2; ++mt)
        #pragma unroll
        for (int nt = 0; nt < 4; ++nt) acc[mt][nt] = (floatx4){0.f, 0.f, 0.f, 0.f};

    float4 pa[4];
    // prefetch A tile 0, write -> buf0; DMA B tile 0 -> buf0
    pa[0] = *(const float4*)(ap0);     pa[1] = *(const float4*)(ap0 + 4);
    pa[2] = *(const float4*)(ap1);     pa[3] = *(const float4*)(ap1 + 4);
    {
        short8* as = smem; short8* bs = smem + 512;
        union { short8 v; unsigned int u[4]; } ta;
        ta.u[0] = pk2(pa[0].x, pa[0].y); ta.u[1] = pk2(pa[0].z, pa[0].w);
        ta.u[2] = pk2(pa[1].x, pa[1].y); ta.u[3] = pk2(pa[1].z, pa[1].w);
        as[adst0] = ta.v;
        ta.u[0] = pk2(pa[2].x, pa[2].y); ta.u[1] = pk2(pa[2].z, pa[2].w);
        ta.u[2] = pk2(pa[3].x, pa[3].y); ta.u[3] = pk2(pa[3].z, pa[3].w);
        as[adst1] = ta.v;
        #pragma unroll
        for (int j = 0; j < 4; ++j)
            dma16(bsrc[j], bs + j * 256 + w * 64);
    }
    // prefetch A tile 1
    pa[0] = *(const float4*)(ap0 + 64);  pa[1] = *(const float4*)(ap0 + 68);
    pa[2] = *(const float4*)(ap1 + 64);  pa[3] = *(const float4*)(ap1 + 68);
    __syncthreads();

    for (int kt = 0; kt < 8; ++kt) {
        short8* as  = smem + (kt & 1) * 1536;
        short8* bs  = as + 512;
        short8* asn = smem + ((kt + 1) & 1) * 1536;
        short8* bsn = asn + 512;
        if (kt < 7) {              // stage tile kt+1 -> other buf
            union { short8 v; unsigned int u[4]; } ta;
            ta.u[0] = pk2(pa[0].x, pa[0].y); ta.u[1] = pk2(pa[0].z, pa[0].w);
            ta.u[2] = pk2(pa[1].x, pa[1].y); ta.u[3] = pk2(pa[1].z, pa[1].w);
            asn[adst0] = ta.v;
            ta.u[0] = pk2(pa[2].x, pa[2].y); ta.u[1] = pk2(pa[2].z, pa[2].w);
            ta.u[2] = pk2(pa[3].x, pa[3].y); ta.u[3] = pk2(pa[3].z, pa[3].w);
            asn[adst1] = ta.v;
            #pragma unroll
            for (int j = 0; j < 4; ++j)
                dma16(bsrc[j] + (kt + 1) * 64, bsn + j * 256 + w * 64);
        }
        if (kt < 6) {              // prefetch A tile kt+2
            const int o = (kt + 2) * 64;
            pa[0] = *(const float4*)(ap0 + o);  pa[1] = *(const float4*)(ap0 + o + 4);
            pa[2] = *(const float4*)(ap1 + o);  pa[3] = *(const float4*)(ap1 + o + 4);
        }
        #pragma unroll
        for (int s = 0; s < 2; ++s) {
            short8 af[2], bfr[4];
            #pragma unroll
            for (int mt = 0; mt < 2; ++mt)
                af[mt] = as[(wr * 32 + mt * 16 + m) * 8 + ((s * 4 + q) ^ (m & 7))];
            #pragma unroll
            for (int nt = 0; nt < 4; ++nt)
                bfr[nt] = bs[(wc * 64 + nt * 16 + m) * 8 + ((s * 4 + q) ^ (m & 7))];
            #pragma unroll
            for (int mt = 0; mt < 2; ++mt)
                #pragma unroll
                for (int nt = 0; nt < 4; ++nt)
                    acc[mt][nt] = __builtin_amdgcn_mfma_f32_16x16x32_bf16(af[mt], bfr[nt], acc[mt][nt], 0, 0, 0);
        }
        __syncthreads();
    }

    if (mat < 2) {
        const float* g = (mat == 0) ? qg : kg;
        const float* be = (mat == 0) ? qbeta : kbeta;
        unsigned short* Y = (mat == 0) ? Qb : Kb;
        float gv[4], bv[4];
        #pragma unroll
        for (int nt = 0; nt < 4; ++nt) { gv[nt] = g[nt * 16 + m]; bv[nt] = be[nt * 16 + m]; }
        #pragma unroll
        for (int mt = 0; mt < 2; ++mt) {
            #pragma unroll
            for (int r = 0; r < 4; ++r) {
                float s = 0.f, sq = 0.f;
                #pragma unroll
                for (int nt = 0; nt < 4; ++nt) { const float v = acc[mt][nt][r]; s += v; sq += v * v; }
                s  += __shfl_xor(s, 1);  s  += __shfl_xor(s, 2);  s  += __shfl_xor(s, 4);  s  += __shfl_xor(s, 8);
                sq += __shfl_xor(sq, 1); sq += __shfl_xor(sq, 2); sq += __shfl_xor(sq, 4); sq += __shfl_xor(sq, 8);
                const float mean = s * (1.f / HD);
                const float var  = sq * (1.f / HD) - mean * mean;
                const float rr   = rsqrtf(var + EPS);
                const int grow = row0 + wr * 32 + mt * 16 + q * 4 + r;
                #pragma unroll
                for (int nt = 0; nt < 4; ++nt) {
                    float v = (acc[mt][nt][r] - mean) * rr * gv[nt] + bv[nt];
                    if (mat == 0) v *= QSCALE;
                    const int col = col0 + wc * 64 + nt * 16 + m;
                    int scol = col;
                    if (mat == 1) {   // K: seg-swizzle within head slice by n
                        const int o = col & 63, sg2 = o >> 3;
                        scol = (col & ~63) | (((sg2 ^ (grow & 7)) << 3) | (o & 7));
                    }
                    Y[(size_t)grow * DIM + scol] = f2bf(v);
                }
            }
        }
    } else {
        // V: transpose via LDS (stride 88), then pack VTb_new[h][chunk][item]
        // item(d,g) = dl*8 + (g^(dl&7)); value = rows {pos..pos+3, pos+16..+19}
        unsigned short* vt = (unsigned short*)smem;
        __syncthreads();
        #pragma unroll
        for (int mt = 0; mt < 2; ++mt)
            #pragma unroll
            for (int nt = 0; nt < 4; ++nt) {
                const int c  = wc * 64 + nt * 16 + m;
                const int rw = wr * 32 + mt * 16 + q * 4;
                *(unsigned int*)(vt + c * 88 + rw)     = pk2(acc[mt][nt][0], acc[mt][nt][1]);
                *(unsigned int*)(vt + c * 88 + rw + 2) = pk2(acc[mt][nt][2], acc[mt][nt][3]);
            }
        __syncthreads();
        #pragma unroll
        for (int p = 0; p < 4; ++p) {
            const int idx = p * 256 + tid;       // 1024 = 128 c x 8 g
            const int c = idx >> 3, g = idx & 7;
            const int dglob = col0 + c, hh = dglob >> 6, dl = dglob & 63;
            const int pos = (g >> 2) * 32 + (g & 3) * 4;
            union { short8 v; ushort4 h4[2]; } tv;
            tv.h4[0] = *(const ushort4*)(vt + c * 88 + pos);
            tv.h4[1] = *(const ushort4*)(vt + c * 88 + pos + 16);
            *(short8*)(VTb + ((size_t)(hh * 64 + blockIdx.x) * 512
                              + dl * 8 + (g ^ (dl & 7))) * 8) = tv.v;
        }
    }
}

// ---------------------------------------------------------------------------
// attn_kernel R10: register-P + ping-pong; K/V staged by global_load_lds DMA
// from pre-swizzled Kb / chunk-packed VTb (zero staging VALU / LDS writes).
// mt=2 (128 q-rows/block), grid (256,4), 32 KB LDS.
// ---------------------------------------------------------------------------
__global__ __launch_bounds__(256) void attn_kernel(
    const unsigned short* __restrict__ Qb, const unsigned short* __restrict__ Kb,
    const unsigned short* __restrict__ VTb, unsigned short* __restrict__ AOp,
    float* __restrict__ sums)
{
    __shared__ short8 smem[2048];       // 32 KB: buf p: ks = +p*1024, vts = +p*1024+512
    const int tid  = threadIdx.x;
    const int w    = tid >> 6;
    const int lane = tid & 63;
    const int m    = lane & 15;
    const int Qd   = lane >> 4;
    const int h    = blockIdx.x & 7;
    const int qgi  = blockIdx.x >> 3;        // 0..31
    const int row0 = qgi * 128;
    const int part = blockIdx.y;
    const int c0   = part * 16;              // first chunk index

    // per-lane DMA sources (chunk-relative), 2 items each for K and V
    const int it0 = tid, it1 = tid + 256;    // item indices
    const unsigned short* ksrc0 = Kb + (size_t)(it0 >> 3) * DIM + h * HD + (it0 & 7) * 8;
    const unsigned short* ksrc1 = Kb + (size_t)(it1 >> 3) * DIM + h * HD + (it1 & 7) * 8;
    const unsigned short* vbase = VTb + (size_t)h * 64 * 512 * 8;

    short8 qf[2][2];
    #pragma unroll
    for (int mt = 0; mt < 2; ++mt)
        #pragma unroll
        for (int s = 0; s < 2; ++s)
            qf[mt][s] = *(const short8*)(Qb + (size_t)(row0 + w * 32 + mt * 16 + m) * DIM
                                         + h * HD + s * 32 + Qd * 8);

    floatx4 of[4][2];
    float sump[2] = {0.f, 0.f};
    #pragma unroll
    for (int t = 0; t < 4; ++t)
        #pragma unroll
        for (int mt = 0; mt < 2; ++mt) of[t][mt] = (floatx4){0.f, 0.f, 0.f, 0.f};

    // prologue: DMA chunk c0 -> buf0
    {
        short8* ks = smem; short8* vts = smem + 512;
        dma16(ksrc0 + (size_t)c0 * 64 * DIM, ks + w * 64);
        dma16(ksrc1 + (size_t)c0 * 64 * DIM, ks + 256 + w * 64);
        dma16(vbase + ((size_t)c0 * 512 + it0) * 8, vts + w * 64);
        dma16(vbase + ((size_t)c0 * 512 + it1) * 8, vts + 256 + w * 64);
    }
    __syncthreads();

    for (int c = 0; c < 16; ++c) {
        short8* ks  = smem + (c & 1) * 1024;
        short8* vts = ks + 512;
        if (c < 15) {             // DMA chunk c+1 -> other buf (overlaps compute)
            short8* ksn  = smem + ((c + 1) & 1) * 1024;
            short8* vtsn = ksn + 512;
            const size_t nc = c0 + c + 1;
            dma16(ksrc0 + nc * 64 * DIM, ksn + w * 64);
            dma16(ksrc1 + nc * 64 * DIM, ksn + 256 + w * 64);
            dma16(vbase + (nc * 512 + it0) * 8, vtsn + w * 64);
            dma16(vbase + (nc * 512 + it1) * 8, vtsn + 256 + w * 64);
        }

        // ---- S^T = K Q^T ----
        floatx4 st[4][2];
        #pragma unroll
        for (int t = 0; t < 4; ++t)
            #pragma unroll
            for (int mt = 0; mt < 2; ++mt) st[t][mt] = (floatx4){0.f, 0.f, 0.f, 0.f};
        #pragma unroll
        for (int s = 0; s < 2; ++s)
            #pragma unroll
            for (int t = 0; t < 4; ++t) {
                const short8 kf = ks[(t * 16 + m) * 8 + ((s * 4 + Qd) ^ (m & 7))];
                #pragma unroll
                for (int mt = 0; mt < 2; ++mt)
                    st[t][mt] = __builtin_amdgcn_mfma_f32_16x16x32_bf16(kf, qf[mt][s], st[t][mt], 0, 0, 0);
            }

        // ---- P = exp(S^T); row-sum partials; pack B-frags ----
        float p[4][2][4];
        #pragma unroll
        for (int t = 0; t < 4; ++t)
            #pragma unroll
            for (int mt = 0; mt < 2; ++mt)
                #pragma unroll
                for (int r = 0; r < 4; ++r) {
                    const float e = __expf(st[t][mt][r]);
                    p[t][mt][r] = e;
                    sump[mt] += e;
                }
        union { short8 v; unsigned int u[4]; } pf[2][2];
        #pragma unroll
        for (int mt = 0; mt < 2; ++mt)
            #pragma unroll
            for (int s2 = 0; s2 < 2; ++s2)
                #pragma unroll
                for (int u = 0; u < 4; ++u)
                    pf[mt][s2].u[u] = pk2(p[s2 * 2 + (u >> 1)][mt][(u & 1) * 2],
                                          p[s2 * 2 + (u >> 1)][mt][(u & 1) * 2 + 1]);

        // ---- O^T += V^T P ----
        #pragma unroll
        for (int s2 = 0; s2 < 2; ++s2)
            #pragma unroll
            for (int t2 = 0; t2 < 4; ++t2) {
                const short8 vf = vts[(t2 * 16 + m) * 8 + ((s2 * 4 + Qd) ^ (m & 7))];
                #pragma unroll
                for (int mt = 0; mt < 2; ++mt)
                    of[t2][mt] = __builtin_amdgcn_mfma_f32_16x16x32_bf16(vf, pf[mt][s2].v, of[t2][mt], 0, 0, 0);
            }
        __syncthreads();
    }

    // ---- denominators ----
    #pragma unroll
    for (int mt = 0; mt < 2; ++mt) {
        float s = sump[mt];
        s += __shfl_xor(s, 16);
        s += __shfl_xor(s, 32);
        sump[mt] = s;
    }
    if (Qd == 0) {
        #pragma unroll
        for (int mt = 0; mt < 2; ++mt)
            sums[((size_t)part * NQROWS + row0 + w * 32 + mt * 16 + m) * NHEAD + h] = sump[mt];
    }

    // ---- O^T -> O via LDS, coalesced bf16 b128 stores ----
    unsigned int* ob = (unsigned int*)smem;
    #pragma unroll
    for (int t2 = 0; t2 < 4; ++t2)
        #pragma unroll
        for (int mt = 0; mt < 2; ++mt) {
            const int qq  = w * 32 + mt * 16 + m;
            const int blk = t2 * 2 + (Qd >> 1);
            const int sub = (Qd & 1) * 2;
            const int bs  = (blk ^ (qq & 7)) * 4;
            ob[qq * 32 + bs + sub]     = pk2(of[t2][mt][0], of[t2][mt][1]);
            ob[qq * 32 + bs + sub + 1] = pk2(of[t2][mt][2], of[t2][mt][3]);
        }
    __syncthreads();
    #pragma unroll
    for (int pp = 0; pp < 4; ++pp) {
        const int idx = tid + pp * 256;
        const int qq = idx >> 3, sg = idx & 7;
        *(short8*)(AOp + (size_t)part * PART_ELEMS + (size_t)(row0 + qq) * DIM + h * HD + sg * 8) =
            smem[qq * 8 + (sg ^ (qq & 7))];
    }
}

// ---------------------------------------------------------------------------
// combine_kernel R10: AO = LN_512( (sum_p O_p)/(sum_p s_p) ), bf16,
// stored SEG-SWIZZLED for final's DMA staging.
// ---------------------------------------------------------------------------
__global__ __launch_bounds__(256) void combine_kernel(
    const unsigned short* __restrict__ AOp, const float* __restrict__ sums,
    const float* __restrict__ g, const float* __restrict__ be,
    unsigned short* __restrict__ AO)
{
    __shared__ float rs[256], rq[256], sm[2], sr[2];
    const int tid  = threadIdx.x;
    const int half = tid >> 7;
    const int row  = blockIdx.x * 2 + half;
    const int t    = tid & 127;                 // 4 cols per thread
    const int h    = t >> 4;

    float stot = 0.f;
    #pragma unroll
    for (int p = 0; p < 4; ++p)
        stot += sums[((size_t)p * NQROWS + row) * NHEAD + h];

    float o[4] = {0.f, 0.f, 0.f, 0.f};
    #pragma unroll
    for (int p = 0; p < 4; ++p) {
        const ushort4 u = *(const ushort4*)(AOp + (size_t)p * PART_ELEMS + (size_t)row * DIM + t * 4);
        o[0] += bf2f(u.x); o[1] += bf2f(u.y); o[2] += bf2f(u.z); o[3] += bf2f(u.w);
    }
    const float inv = 1.0f / stot;
    const float v0 = o[0] * inv, v1 = o[1] * inv, v2 = o[2] * inv, v3 = o[3] * inv;

    rs[tid] = v0 + v1 + v2 + v3;
    rq[tid] = v0 * v0 + v1 * v1 + v2 * v2 + v3 * v3;
    __syncthreads();
    #pragma unroll
    for (int off = 64; off > 0; off >>= 1) {
        if (t < off) { rs[tid] += rs[tid + off]; rq[tid] += rq[tid + off]; }
        __syncthreads();
    }
    if (t == 0) {
        const float mean = rs[tid] * (1.f / DIM);
        const float var  = rq[tid] * (1.f / DIM) - mean * mean;
        sm[half] = mean;
        sr[half] = rsqrtf(var + EPS);
    }
    __syncthreads();

    const float mean = sm[half], rstd = sr[half];
    const float4 g4 = *(const float4*)(g + t * 4);
    const float4 b4 = *(const float4*)(be + t * 4);
    uint2 packed;
    packed.x = pk2((v0 - mean) * rstd * g4.x + b4.x, (v1 - mean) * rstd * g4.y + b4.y);
    packed.y = pk2((v2 - mean) * rstd * g4.z + b4.z, (v3 - mean) * rstd * g4.w + b4.w);
    const int kt = t >> 4, seg = (t >> 1) & 7, jof = (t & 1) * 4;
    *(uint2*)(AO + (size_t)row * DIM + kt * 64 + ((seg ^ (row & 7)) << 3) + jof) = packed;
}

// ---------------------------------------------------------------------------
// final_kernel R10: pure bf16 GEMM out = AO @ Wproj^T; BOTH operands staged
// via global_load_lds DMA from pre-swizzled AO / Wb.  Ping-pong, 32 KB.
// ---------------------------------------------------------------------------
__global__ __launch_bounds__(256) void final_kernel(
    const unsigned short* __restrict__ AO, const unsigned short* __restrict__ Wpb,
    float* __restrict__ out)
{
    __shared__ short8 fs[2048];            // buf p = fs + p*1024 (A 512 | B 512)
    const int tid  = threadIdx.x;
    const int w    = tid >> 6, lane = tid & 63, m = lane & 15, q = lane >> 4;
    const int row0 = blockIdx.x * 64;
    const int col0 = blockIdx.y * 64;

    const int it0 = tid, it1 = tid + 256;
    const unsigned short* asrc0 = AO  + (size_t)(row0 + (it0 >> 3)) * DIM + (it0 & 7) * 8;
    const unsigned short* asrc1 = AO  + (size_t)(row0 + (it1 >> 3)) * DIM + (it1 & 7) * 8;
    const unsigned short* wsrc0 = Wpb + (size_t)(col0 + (it0 >> 3)) * DIM + (it0 & 7) * 8;
    const unsigned short* wsrc1 = Wpb + (size_t)(col0 + (it1 >> 3)) * DIM + (it1 & 7) * 8;

    floatx4 acc[4];
    #pragma unroll
    for (int mt = 0; mt < 4; ++mt) acc[mt] = (floatx4){0.f, 0.f, 0.f, 0.f};

    {   // DMA tile 0 -> buf0
        dma16(asrc0, fs + w * 64);
        dma16(asrc1, fs + 256 + w * 64);
        dma16(wsrc0, fs + 512 + w * 64);
        dma16(wsrc1, fs + 768 + w * 64);
    }
    __syncthreads();

    for (int kt = 0; kt < 8; ++kt) {
        short8* buf  = fs + (kt & 1) * 1024;
        if (kt < 7) {
            short8* bufn = fs + ((kt + 1) & 1) * 1024;
            const int o = (kt + 1) * 64;
            dma16(asrc0 + o, bufn + w * 64);
            dma16(asrc1 + o, bufn + 256 + w * 64);
            dma16(wsrc0 + o, bufn + 512 + w * 64);
            dma16(wsrc1 + o, bufn + 768 + w * 64);
        }
        #pragma unroll
        for (int s = 0; s < 2; ++s) {
            short8 af[4];
            #pragma unroll
            for (int mt = 0; mt < 4; ++mt)
                af[mt] = buf[(mt * 16 + m) * 8 + ((s * 4 + q) ^ (m & 7))];
            const short8 bfr = buf[512 + (w * 16 + m) * 8 + ((s * 4 + q) ^ (m & 7))];
            #pragma unroll
            for (int mt = 0; mt < 4; ++mt)
                acc[mt] = __builtin_amdgcn_mfma_f32_16x16x32_bf16(af[mt], bfr, acc[mt], 0, 0, 0);
        }
        __syncthreads();
    }

    #pragma unroll
    for (int mt = 0; mt < 4; ++mt)
        #pragma unroll
        for (int r = 0; r < 4; ++r)
            out[(size_t)(row0 + mt * 16 + q * 4 + r) * DIM + col0 + w * 16 + m] = acc[mt][r];
}

// ---------------------------------------------------------------------------
extern "C" void kernel_launch(void* const* d_in, const int* in_sizes, int n_in,
                              void* d_out, int out_size, void* d_ws, size_t ws_size,
                              hipStream_t stream)
{
    const float* x_q = (const float*)d_in[0];
    const float* x_k = (const float*)d_in[1];
    const float* x_v = (const float*)d_in[2];
    const float* Wq  = (const float*)d_in[3];
    const float* Wk  = (const float*)d_in[4];
    const float* Wv  = (const float*)d_in[5];
    const float* Wp  = (const float*)d_in[6];
    const float* qg  = (const float*)d_in[7];
    const float* qb  = (const float*)d_in[8];
    const float* kg  = (const float*)d_in[9];
    const float* kb  = (const float*)d_in[10];
    const float* ng  = (const float*)d_in[11];
    const float* nb  = (const float*)d_in[12];
    float* out = (float*)d_out;

    // ws: Qb|Kb|VTb (bf16, 4 MB each) | AOp (4x4 MB) | sums 512 KB | Wb 2 MB.
    unsigned short* Qb   = (unsigned short*)d_ws;
    unsigned short* Kb   = Qb  + (size_t)NQROWS * DIM;
    unsigned short* VTb  = Kb  + (size_t)NBANK * DIM;
    unsigned short* AOp  = VTb + (size_t)NBANK * DIM;
    float*          sums = (float*)(AOp + (size_t)4 * PART_ELEMS);
    unsigned short* Wb   = (unsigned short*)(sums + (size_t)4 * NQROWS * NHEAD);
    unsigned short* AO   = Qb;   // alias: Qb dead after attn_kernel

    wcvt_kernel<<<dim3(128, 4), 256, 0, stream>>>(Wq, Wk, Wv, Wp, Wb);
    qkv_kernel<<<dim3(64, 12), 256, 0, stream>>>(x_q, x_k, x_v, Wb,
                                                 qg, qb, kg, kb, Qb, Kb, VTb);
    attn_kernel<<<dim3(256, 4), 256, 0, stream>>>(Qb, Kb, VTb, AOp, sums);
    combine_kernel<<<NQROWS / 2, 256, 0, stream>>>(AOp, sums, ng, nb, AO);
    final_kernel<<<dim3(64, 8), 256, 0, stream>>>(AO, Wb + (size_t)3 * DIM * DIM, out);
}